// Round 1
// baseline (940.188 us; speedup 1.0000x reference)
//
#include <hip/hip_runtime.h>
#include <math.h>

#define BATCH 2048
#define CH 512
#define N_COARSE 256
#define F_FINE 256
#define K_TOP 4
#define OUT_STRIDE 65537  // 1 + N*F

__device__ __forceinline__ float gelu_tanh(float x) {
    // jax.nn.gelu default (approximate=True)
    float x3 = x * x * x;
    float t = tanhf(0.7978845608028654f * (x + 0.044715f * x3));
    return 0.5f * x * (1.0f + t);
}

// ---------------- LN(x) + no_op dot ----------------
__global__ __launch_bounds__(256) void ln_noop_kernel(
    const float* __restrict__ x, const float* __restrict__ g, const float* __restrict__ b,
    const float* __restrict__ nop_w, const float* __restrict__ nop_b,
    float* __restrict__ xn, float* __restrict__ out)
{
    int row = blockIdx.x;
    int t = threadIdx.x;
    int lane = t & 63, wave = t >> 6;
    const float* xr = x + (size_t)row * CH;
    float v0 = xr[t], v1 = xr[t + 256];
    float s = v0 + v1, ss = v0 * v0 + v1 * v1;
    #pragma unroll
    for (int off = 32; off; off >>= 1) { s += __shfl_xor(s, off); ss += __shfl_xor(ss, off); }
    __shared__ float red[8];
    if (lane == 0) { red[wave] = s; red[4 + wave] = ss; }
    __syncthreads();
    s = red[0] + red[1] + red[2] + red[3];
    ss = red[4] + red[5] + red[6] + red[7];
    float mean = s * (1.0f / CH);
    float var = ss * (1.0f / CH) - mean * mean;
    float rsq = rsqrtf(var + 1e-5f);
    float xn0 = (v0 - mean) * rsq * g[t] + b[t];
    float xn1 = (v1 - mean) * rsq * g[t + 256] + b[t + 256];
    float* xnr = xn + (size_t)row * CH;
    xnr[t] = xn0; xnr[t + 256] = xn1;
    // no_op = xn . nop_w + nop_b
    float d = xn0 * nop_w[t] + xn1 * nop_w[t + 256];
    #pragma unroll
    for (int off = 32; off; off >>= 1) d += __shfl_xor(d, off);
    __syncthreads();
    if (lane == 0) red[wave] = d;
    __syncthreads();
    if (t == 0) out[(size_t)row * OUT_STRIDE] = red[0] + red[1] + red[2] + red[3] + nop_b[0];
}

// ---------------- LN of gathered emb rows ----------------
__global__ __launch_bounds__(256) void emb_ln_kernel(
    const float* __restrict__ emb, const float* __restrict__ g, const float* __restrict__ b,
    const int* __restrict__ idx, float* __restrict__ e_ln)
{
    int blk = blockIdx.x;           // b*4+k
    int t = threadIdx.x;
    int lane = t & 63, wave = t >> 6;
    int n = idx[blk];
    const float* er = emb + (size_t)n * CH;
    float v0 = er[t], v1 = er[t + 256];
    float s = v0 + v1, ss = v0 * v0 + v1 * v1;
    #pragma unroll
    for (int off = 32; off; off >>= 1) { s += __shfl_xor(s, off); ss += __shfl_xor(ss, off); }
    __shared__ float red[8];
    if (lane == 0) { red[wave] = s; red[4 + wave] = ss; }
    __syncthreads();
    s = red[0] + red[1] + red[2] + red[3];
    ss = red[4] + red[5] + red[6] + red[7];
    float mean = s * (1.0f / CH);
    float var = ss * (1.0f / CH) - mean * mean;
    float rsq = rsqrtf(var + 1e-5f);
    float* orow = e_ln + (size_t)blk * CH;
    orow[t] = (v0 - mean) * rsq * g[t] + b[t];
    orow[t + 256] = (v1 - mean) * rsq * g[t + 256] + b[t + 256];
}

// ---------------- tiled fp32 GEMM: C = [gelu]( A@W + bias [+ Add[m/div]] ) ----------------
// A: M x Kd (row major), W: Kd x Nd (row major). M%64==0, Nd%64==0, Kd%16==0.
template<bool GELU, bool ADD>
__global__ __launch_bounds__(256) void gemm_kernel(
    const float* __restrict__ A, const float* __restrict__ W,
    const float* __restrict__ bias, const float* __restrict__ Add, int adddiv,
    float* __restrict__ Cmat, int M, int Nd, int Kd)
{
    __shared__ float As[16][68];
    __shared__ float Ws[16][68];
    int tid = threadIdx.x;
    int tx = tid & 15, ty = tid >> 4;
    int n0 = blockIdx.x * 64, m0 = blockIdx.y * 64;

    int lm = tid >> 2;            // 0..63 (A row within tile)
    int lk = (tid & 3) * 4;       // 0,4,8,12
    int wn = (tid & 15) * 4;      // 0..60
    int wk = tid >> 4;            // 0..15

    const float* Aptr = A + (size_t)(m0 + lm) * Kd + lk;
    const float* Wptr = W + (size_t)wk * Nd + n0 + wn;

    float acc[4][4] = {};

    for (int k0 = 0; k0 < Kd; k0 += 16) {
        float4 av = *(const float4*)(Aptr + k0);
        float4 wv = *(const float4*)(Wptr + (size_t)k0 * Nd);
        As[lk + 0][lm] = av.x; As[lk + 1][lm] = av.y;
        As[lk + 2][lm] = av.z; As[lk + 3][lm] = av.w;
        *(float4*)&Ws[wk][wn] = wv;
        __syncthreads();
        #pragma unroll
        for (int kk = 0; kk < 16; ++kk) {
            float4 a = *(const float4*)&As[kk][ty * 4];
            float4 w = *(const float4*)&Ws[kk][tx * 4];
            acc[0][0] += a.x * w.x; acc[0][1] += a.x * w.y; acc[0][2] += a.x * w.z; acc[0][3] += a.x * w.w;
            acc[1][0] += a.y * w.x; acc[1][1] += a.y * w.y; acc[1][2] += a.y * w.z; acc[1][3] += a.y * w.w;
            acc[2][0] += a.z * w.x; acc[2][1] += a.z * w.y; acc[2][2] += a.z * w.z; acc[2][3] += a.z * w.w;
            acc[3][0] += a.w * w.x; acc[3][1] += a.w * w.y; acc[3][2] += a.w * w.z; acc[3][3] += a.w * w.w;
        }
        __syncthreads();
    }

    #pragma unroll
    for (int i = 0; i < 4; ++i) {
        int gm = m0 + ty * 4 + i;
        int gn0 = n0 + tx * 4;
        float4 o;
        float* po = &o.x;
        #pragma unroll
        for (int j = 0; j < 4; ++j) {
            float v = acc[i][j];
            if (bias) v += bias[gn0 + j];
            if (ADD) v += Add[(size_t)(gm / adddiv) * Nd + gn0 + j];
            if (GELU) v = gelu_tanh(v);
            po[j] = v;
        }
        *(float4*)&Cmat[(size_t)gm * Nd + gn0] = o;
    }
}

// ---------------- top-4 per row of coarse (one wave per row) ----------------
__global__ __launch_bounds__(64) void topk_kernel(
    const float* __restrict__ coarse, int* __restrict__ idx, float* __restrict__ cvals)
{
    int row = blockIdx.x;
    int lane = threadIdx.x;
    const float* cr = coarse + (size_t)row * N_COARSE;
    float v[4]; int id[4];
    #pragma unroll
    for (int j = 0; j < 4; ++j) { v[j] = cr[lane + 64 * j]; id[j] = lane + 64 * j; }
    #pragma unroll
    for (int r = 0; r < K_TOP; ++r) {
        float bv = v[0]; int bi = id[0];
        #pragma unroll
        for (int j = 1; j < 4; ++j)
            if (v[j] > bv || (v[j] == bv && id[j] < bi)) { bv = v[j]; bi = id[j]; }
        #pragma unroll
        for (int off = 32; off; off >>= 1) {
            float ov = __shfl_xor(bv, off); int oi = __shfl_xor(bi, off);
            if (ov > bv || (ov == bv && oi < bi)) { bv = ov; bi = oi; }
        }
        // all lanes agree now; owner masks out
        if ((bi & 63) == lane) v[bi >> 6] = -INFINITY;
        if (lane == 0) { idx[row * K_TOP + r] = bi; cvals[row * K_TOP + r] = bv; }
    }
}

// ---------------- log_softmax over fine rows + add coarse val (in place) ----------------
__global__ __launch_bounds__(64) void logsm_kernel(
    float* __restrict__ fine, const float* __restrict__ cvals)
{
    int row = blockIdx.x;   // b*4+k
    int lane = threadIdx.x;
    float* fr = fine + (size_t)row * F_FINE;
    float v[4];
    #pragma unroll
    for (int j = 0; j < 4; ++j) v[j] = fr[lane + 64 * j];
    float mx = fmaxf(fmaxf(v[0], v[1]), fmaxf(v[2], v[3]));
    #pragma unroll
    for (int off = 32; off; off >>= 1) mx = fmaxf(mx, __shfl_xor(mx, off));
    float se = 0.f;
    #pragma unroll
    for (int j = 0; j < 4; ++j) se += expf(v[j] - mx);
    #pragma unroll
    for (int off = 32; off; off >>= 1) se += __shfl_xor(se, off);
    float addc = cvals[row] - mx - logf(se);
    #pragma unroll
    for (int j = 0; j < 4; ++j) fr[lane + 64 * j] = v[j] + addc;
}

// ---------------- final scatter into permuted dense output ----------------
__global__ __launch_bounds__(256) void scatter_kernel(
    const float* __restrict__ coarse, const float* __restrict__ fine,
    const int* __restrict__ idx, float* __restrict__ out)
{
    const float LOG_F = 5.545177444479562f;
    int b = blockIdx.y;
    int o = (blockIdx.x * 256 + threadIdx.x) * 4;   // 0..65532
    int c0 = o >> 12, f0 = (o >> 8) & 15, c1 = (o >> 4) & 15, f1 = o & 15;
    int n = c0 * 16 + c1;
    int f = f0 * 16 + f1;
    int i0 = idx[b * 4 + 0], i1 = idx[b * 4 + 1], i2 = idx[b * 4 + 2], i3 = idx[b * 4 + 3];
    int k = -1;
    if (n == i0) k = 0; else if (n == i1) k = 1; else if (n == i2) k = 2; else if (n == i3) k = 3;
    float r0, r1, r2, r3;
    if (k >= 0) {
        const float* fr = fine + ((size_t)(b * 4 + k)) * F_FINE + f;
        r0 = fr[0]; r1 = fr[1]; r2 = fr[2]; r3 = fr[3];
    } else {
        float base = coarse[(size_t)b * N_COARSE + n] - LOG_F;
        r0 = r1 = r2 = r3 = base;
    }
    size_t ob = (size_t)b * OUT_STRIDE + 1 + o;
    out[ob + 0] = r0; out[ob + 1] = r1; out[ob + 2] = r2; out[ob + 3] = r3;
}

extern "C" void kernel_launch(void* const* d_in, const int* in_sizes, int n_in,
                              void* d_out, int out_size, void* d_ws, size_t ws_size,
                              hipStream_t stream) {
    const float* x     = (const float*)d_in[0];
    const float* in_g  = (const float*)d_in[1];
    const float* in_b  = (const float*)d_in[2];
    const float* nop_w = (const float*)d_in[3];
    const float* nop_b = (const float*)d_in[4];
    const float* c_w1  = (const float*)d_in[5];
    const float* c_b1  = (const float*)d_in[6];
    const float* c_w2  = (const float*)d_in[7];
    const float* c_b2  = (const float*)d_in[8];
    const float* c_w3  = (const float*)d_in[9];
    const float* c_b3  = (const float*)d_in[10];
    const float* emb   = (const float*)d_in[11];
    const float* emb_g = (const float*)d_in[12];
    const float* emb_b = (const float*)d_in[13];
    const float* f_w1  = (const float*)d_in[14];
    const float* f_b1  = (const float*)d_in[15];
    const float* f_w2  = (const float*)d_in[16];
    const float* f_b2  = (const float*)d_in[17];
    const float* f_w3  = (const float*)d_in[18];
    const float* f_b3  = (const float*)d_in[19];

    float* ws = (float*)d_ws;
    float* xn     = ws;                       // 2048*512
    float* h1     = xn + 1048576;             // 2048*512
    float* h2     = h1 + 1048576;             // 2048*512
    float* coarse = h2 + 1048576;             // 2048*256
    float* ga     = coarse + 524288;          // 2048*512  (xn @ f_w1_top)
    float* e_ln   = ga + 1048576;             // 8192*512
    float* fh1    = e_ln + 4194304;           // 8192*512
    float* fh2    = fh1 + 4194304;            // 8192*512
    float* fine   = fh2 + 4194304;            // 8192*256
    int*   idxb   = (int*)(fine + 2097152);   // 8192
    float* cvals  = (float*)(idxb + 8192);    // 8192

    float* out = (float*)d_out;

    // 1. LN + no_op
    ln_noop_kernel<<<BATCH, 256, 0, stream>>>(x, in_g, in_b, nop_w, nop_b, xn, out);
    // 2-4. coarse MLP (fp32 for top-k fidelity)
    gemm_kernel<true, false><<<dim3(8, 32), 256, 0, stream>>>(xn, c_w1, c_b1, nullptr, 1, h1, 2048, 512, 512);
    gemm_kernel<true, false><<<dim3(8, 32), 256, 0, stream>>>(h1, c_w2, c_b2, nullptr, 1, h2, 2048, 512, 512);
    gemm_kernel<false, false><<<dim3(4, 32), 256, 0, stream>>>(h2, c_w3, c_b3, nullptr, 1, coarse, 2048, 256, 512);
    // 5. top-4
    topk_kernel<<<BATCH, 64, 0, stream>>>(coarse, idxb, cvals);
    // 6. gather + LN emb rows
    emb_ln_kernel<<<BATCH * K_TOP, 256, 0, stream>>>(emb, emb_g, emb_b, idxb, e_ln);
    // 7. ga = xn @ f_w1[0:512,:]   (shared across the K=4 candidates)
    gemm_kernel<false, false><<<dim3(8, 32), 256, 0, stream>>>(xn, f_w1, nullptr, nullptr, 1, ga, 2048, 512, 512);
    // 8. fh1 = gelu(e_ln @ f_w1[512:,:] + ga[b] + f_b1)
    gemm_kernel<true, true><<<dim3(8, 128), 256, 0, stream>>>(e_ln, f_w1 + 512 * 512, f_b1, ga, 4, fh1, 8192, 512, 512);
    // 9. fh2 = gelu(fh1 @ f_w2 + f_b2)
    gemm_kernel<true, false><<<dim3(8, 128), 256, 0, stream>>>(fh1, f_w2, f_b2, nullptr, 1, fh2, 8192, 512, 512);
    // 10. fine = fh2 @ f_w3 + f_b3
    gemm_kernel<false, false><<<dim3(4, 128), 256, 0, stream>>>(fh2, f_w3, f_b3, nullptr, 1, fine, 8192, 256, 512);
    // 11. fine = cval + log_softmax(fine)
    logsm_kernel<<<BATCH * K_TOP, 64, 0, stream>>>(fine, cvals);
    // 12. scatter to permuted output
    scatter_kernel<<<dim3(64, BATCH), 256, 0, stream>>>(coarse, fine, idxb, out);
}

// Round 2
// 813.562 us; speedup vs baseline: 1.1556x; 1.1556x over previous
//
#include <hip/hip_runtime.h>
#include <math.h>

#define BATCH 2048
#define CH 512
#define N_COARSE 256
#define F_FINE 256
#define K_TOP 4
#define OUT_STRIDE 65537  // 1 + N*F

typedef unsigned short ushort_t;
typedef __bf16 bf16x8 __attribute__((ext_vector_type(8)));
typedef float f32x4 __attribute__((ext_vector_type(4)));

__device__ __forceinline__ float gelu_tanh(float x) {
    float x3 = x * x * x;
    float t = tanhf(0.7978845608028654f * (x + 0.044715f * x3));
    return 0.5f * x * (1.0f + t);
}

__device__ __forceinline__ ushort_t f2bf(float f) {
    unsigned u = __float_as_uint(f);
    unsigned r = (u + 0x7FFF + ((u >> 16) & 1)) >> 16;
    return (ushort_t)r;
}

// ---------------- LN(x) + no_op dot; writes fp32 xn and bf16 xn ----------------
__global__ __launch_bounds__(256) void ln_noop_kernel(
    const float* __restrict__ x, const float* __restrict__ g, const float* __restrict__ b,
    const float* __restrict__ nop_w, const float* __restrict__ nop_b,
    float* __restrict__ xn, ushort_t* __restrict__ xn_bf, float* __restrict__ out)
{
    int row = blockIdx.x;
    int t = threadIdx.x;
    int lane = t & 63, wave = t >> 6;
    const float* xr = x + (size_t)row * CH;
    float v0 = xr[t], v1 = xr[t + 256];
    float s = v0 + v1, ss = v0 * v0 + v1 * v1;
    #pragma unroll
    for (int off = 32; off; off >>= 1) { s += __shfl_xor(s, off); ss += __shfl_xor(ss, off); }
    __shared__ float red[8];
    if (lane == 0) { red[wave] = s; red[4 + wave] = ss; }
    __syncthreads();
    s = red[0] + red[1] + red[2] + red[3];
    ss = red[4] + red[5] + red[6] + red[7];
    float mean = s * (1.0f / CH);
    float var = ss * (1.0f / CH) - mean * mean;
    float rsq = rsqrtf(var + 1e-5f);
    float xn0 = (v0 - mean) * rsq * g[t] + b[t];
    float xn1 = (v1 - mean) * rsq * g[t + 256] + b[t + 256];
    float* xnr = xn + (size_t)row * CH;
    xnr[t] = xn0; xnr[t + 256] = xn1;
    ushort_t* xbr = xn_bf + (size_t)row * CH;
    xbr[t] = f2bf(xn0); xbr[t + 256] = f2bf(xn1);
    float d = xn0 * nop_w[t] + xn1 * nop_w[t + 256];
    #pragma unroll
    for (int off = 32; off; off >>= 1) d += __shfl_xor(d, off);
    __syncthreads();
    if (lane == 0) red[wave] = d;
    __syncthreads();
    if (t == 0) out[(size_t)row * OUT_STRIDE] = red[0] + red[1] + red[2] + red[3] + nop_b[0];
}

// ---------------- LN of gathered emb rows -> bf16 ----------------
__global__ __launch_bounds__(256) void emb_ln_kernel(
    const float* __restrict__ emb, const float* __restrict__ g, const float* __restrict__ b,
    const int* __restrict__ idx, ushort_t* __restrict__ e_bf)
{
    int blk = blockIdx.x;           // b*4+k
    int t = threadIdx.x;
    int lane = t & 63, wave = t >> 6;
    int n = idx[blk];
    const float* er = emb + (size_t)n * CH;
    float v0 = er[t], v1 = er[t + 256];
    float s = v0 + v1, ss = v0 * v0 + v1 * v1;
    #pragma unroll
    for (int off = 32; off; off >>= 1) { s += __shfl_xor(s, off); ss += __shfl_xor(ss, off); }
    __shared__ float red[8];
    if (lane == 0) { red[wave] = s; red[4 + wave] = ss; }
    __syncthreads();
    s = red[0] + red[1] + red[2] + red[3];
    ss = red[4] + red[5] + red[6] + red[7];
    float mean = s * (1.0f / CH);
    float var = ss * (1.0f / CH) - mean * mean;
    float rsq = rsqrtf(var + 1e-5f);
    ushort_t* orow = e_bf + (size_t)blk * CH;
    orow[t] = f2bf((v0 - mean) * rsq * g[t] + b[t]);
    orow[t + 256] = f2bf((v1 - mean) * rsq * g[t + 256] + b[t + 256]);
}

// ---------------- weight convert + transpose: W (Kd x Nd f32) -> Wt (Nd x Kd bf16) ----------------
__global__ __launch_bounds__(256) void convT_kernel(
    const float* __restrict__ W, ushort_t* __restrict__ Wt, int Kd, int Nd)
{
    __shared__ float s[32][33];
    int tx = threadIdx.x & 31, ty = threadIdx.x >> 5;   // ty 0..7
    int n0 = blockIdx.x * 32, k0 = blockIdx.y * 32;
    #pragma unroll
    for (int i = 0; i < 4; ++i) {
        int r = ty + i * 8;
        s[r][tx] = W[(size_t)(k0 + r) * Nd + n0 + tx];
    }
    __syncthreads();
    #pragma unroll
    for (int i = 0; i < 4; ++i) {
        int r = ty + i * 8;
        Wt[(size_t)(n0 + r) * Kd + k0 + tx] = f2bf(s[tx][r]);
    }
}

// ---------------- fp32 tiled GEMM (coarse path only) ----------------
template<bool GELU>
__global__ __launch_bounds__(256) void gemm_kernel(
    const float* __restrict__ A, const float* __restrict__ W,
    const float* __restrict__ bias, float* __restrict__ Cmat, int M, int Nd, int Kd)
{
    __shared__ float As[16][68];
    __shared__ float Ws[16][68];
    int tid = threadIdx.x;
    int tx = tid & 15, ty = tid >> 4;
    int n0 = blockIdx.x * 64, m0 = blockIdx.y * 64;

    int lm = tid >> 2;
    int lk = (tid & 3) * 4;
    int wn = (tid & 15) * 4;
    int wk = tid >> 4;

    const float* Aptr = A + (size_t)(m0 + lm) * Kd + lk;
    const float* Wptr = W + (size_t)wk * Nd + n0 + wn;

    float acc[4][4] = {};

    for (int k0 = 0; k0 < Kd; k0 += 16) {
        float4 av = *(const float4*)(Aptr + k0);
        float4 wv = *(const float4*)(Wptr + (size_t)k0 * Nd);
        As[lk + 0][lm] = av.x; As[lk + 1][lm] = av.y;
        As[lk + 2][lm] = av.z; As[lk + 3][lm] = av.w;
        *(float4*)&Ws[wk][wn] = wv;
        __syncthreads();
        #pragma unroll
        for (int kk = 0; kk < 16; ++kk) {
            float4 a = *(const float4*)&As[kk][ty * 4];
            float4 w = *(const float4*)&Ws[kk][tx * 4];
            acc[0][0] += a.x * w.x; acc[0][1] += a.x * w.y; acc[0][2] += a.x * w.z; acc[0][3] += a.x * w.w;
            acc[1][0] += a.y * w.x; acc[1][1] += a.y * w.y; acc[1][2] += a.y * w.z; acc[1][3] += a.y * w.w;
            acc[2][0] += a.z * w.x; acc[2][1] += a.z * w.y; acc[2][2] += a.z * w.z; acc[2][3] += a.z * w.w;
            acc[3][0] += a.w * w.x; acc[3][1] += a.w * w.y; acc[3][2] += a.w * w.z; acc[3][3] += a.w * w.w;
        }
        __syncthreads();
    }

    #pragma unroll
    for (int i = 0; i < 4; ++i) {
        int gm = m0 + ty * 4 + i;
        int gn0 = n0 + tx * 4;
        float4 o;
        float* po = &o.x;
        #pragma unroll
        for (int j = 0; j < 4; ++j) {
            float v = acc[i][j] + bias[gn0 + j];
            if (GELU) v = gelu_tanh(v);
            po[j] = v;
        }
        *(float4*)&Cmat[(size_t)gm * Nd + gn0] = o;
    }
}

// ---------------- bf16 MFMA GEMM: 128x128 tile, BK=32, 4 waves of 4x4 16x16x32 frags ----
// A1/A2 bf16; Wt is (Nd x Ktot) bf16 row-major (pre-transposed weights).
// CONCAT: rows m: k<K1 -> A1[m>>2][k] (stride K1), k>=K1 -> A2[m][k-K1] (stride Ktot-K1).
template<bool CONCAT, bool GELU, bool OUT_BF16>
__global__ __launch_bounds__(256) void mfma_gemm_kernel(
    const ushort_t* __restrict__ A1, const ushort_t* __restrict__ A2, int K1,
    const ushort_t* __restrict__ Wt, const float* __restrict__ bias,
    void* __restrict__ Cout, int M, int Nd, int Ktot)
{
    __shared__ ushort_t As[128 * 32];
    __shared__ ushort_t Bs[128 * 32];
    int t = threadIdx.x;
    int n0 = blockIdx.x * 128, m0 = blockIdx.y * 128;
    int wave = t >> 6, lane = t & 63;
    int wm = (wave & 1) * 64, wn = (wave >> 1) * 64;
    int lr = lane & 15, quad = lane >> 4;

    f32x4 acc[4][4] = {};

    for (int k0 = 0; k0 < Ktot; k0 += 32) {
        #pragma unroll
        for (int j = 0; j < 2; ++j) {
            int c = j * 256 + t;
            int r = c >> 2, q = (c & 3) * 8;
            // A chunk
            const ushort_t* ap;
            int gr = m0 + r;
            if (CONCAT) {
                ap = (k0 < K1) ? A1 + (size_t)(gr >> 2) * K1 + k0 + q
                               : A2 + (size_t)gr * (Ktot - K1) + (k0 - K1) + q;
            } else {
                ap = A1 + (size_t)gr * Ktot + k0 + q;
            }
            *(float4*)&As[c * 8] = *(const float4*)ap;
            // B chunk
            *(float4*)&Bs[c * 8] = *(const float4*)(Wt + (size_t)(n0 + r) * Ktot + k0 + q);
        }
        __syncthreads();
        bf16x8 af[4], bfr[4];
        #pragma unroll
        for (int i = 0; i < 4; ++i)
            af[i] = *(const bf16x8*)&As[(wm + i * 16 + lr) * 32 + quad * 8];
        #pragma unroll
        for (int j = 0; j < 4; ++j)
            bfr[j] = *(const bf16x8*)&Bs[(wn + j * 16 + lr) * 32 + quad * 8];
        #pragma unroll
        for (int i = 0; i < 4; ++i)
            #pragma unroll
            for (int j = 0; j < 4; ++j)
                acc[i][j] = __builtin_amdgcn_mfma_f32_16x16x32_bf16(af[i], bfr[j], acc[i][j], 0, 0, 0);
        __syncthreads();
    }

    // epilogue: D row = quad*4+reg, col = lr (within each 16x16 tile)
    #pragma unroll
    for (int j = 0; j < 4; ++j) {
        int col = n0 + wn + j * 16 + lr;
        float bv = bias[col];
        #pragma unroll
        for (int i = 0; i < 4; ++i) {
            #pragma unroll
            for (int r = 0; r < 4; ++r) {
                int row = m0 + wm + i * 16 + quad * 4 + r;
                float val = acc[i][j][r] + bv;
                if (GELU) val = gelu_tanh(val);
                if (OUT_BF16)
                    ((ushort_t*)Cout)[(size_t)row * Nd + col] = f2bf(val);
                else
                    ((float*)Cout)[(size_t)row * Nd + col] = val;
            }
        }
    }
}

// ---------------- top-4 per row of coarse (one wave per row) ----------------
__global__ __launch_bounds__(64) void topk_kernel(
    const float* __restrict__ coarse, int* __restrict__ idx, float* __restrict__ cvals)
{
    int row = blockIdx.x;
    int lane = threadIdx.x;
    const float* cr = coarse + (size_t)row * N_COARSE;
    float v[4]; int id[4];
    #pragma unroll
    for (int j = 0; j < 4; ++j) { v[j] = cr[lane + 64 * j]; id[j] = lane + 64 * j; }
    #pragma unroll
    for (int r = 0; r < K_TOP; ++r) {
        float bv = v[0]; int bi = id[0];
        #pragma unroll
        for (int j = 1; j < 4; ++j)
            if (v[j] > bv || (v[j] == bv && id[j] < bi)) { bv = v[j]; bi = id[j]; }
        #pragma unroll
        for (int off = 32; off; off >>= 1) {
            float ov = __shfl_xor(bv, off); int oi = __shfl_xor(bi, off);
            if (ov > bv || (ov == bv && oi < bi)) { bv = ov; bi = oi; }
        }
        if ((bi & 63) == lane) v[bi >> 6] = -INFINITY;
        if (lane == 0) { idx[row * K_TOP + r] = bi; cvals[row * K_TOP + r] = bv; }
    }
}

// ---------------- log_softmax + coarse val (in place) ----------------
__global__ __launch_bounds__(64) void logsm_kernel(
    float* __restrict__ fine, const float* __restrict__ cvals)
{
    int row = blockIdx.x;
    int lane = threadIdx.x;
    float* fr = fine + (size_t)row * F_FINE;
    float v[4];
    #pragma unroll
    for (int j = 0; j < 4; ++j) v[j] = fr[lane + 64 * j];
    float mx = fmaxf(fmaxf(v[0], v[1]), fmaxf(v[2], v[3]));
    #pragma unroll
    for (int off = 32; off; off >>= 1) mx = fmaxf(mx, __shfl_xor(mx, off));
    float se = 0.f;
    #pragma unroll
    for (int j = 0; j < 4; ++j) se += expf(v[j] - mx);
    #pragma unroll
    for (int off = 32; off; off >>= 1) se += __shfl_xor(se, off);
    float addc = cvals[row] - mx - logf(se);
    #pragma unroll
    for (int j = 0; j < 4; ++j) fr[lane + 64 * j] = v[j] + addc;
}

// ---------------- final scatter into permuted dense output ----------------
__global__ __launch_bounds__(256) void scatter_kernel(
    const float* __restrict__ coarse, const float* __restrict__ fine,
    const int* __restrict__ idx, float* __restrict__ out)
{
    const float LOG_F = 5.545177444479562f;
    int b = blockIdx.y;
    int o = (blockIdx.x * 256 + threadIdx.x) * 4;
    int c0 = o >> 12, f0 = (o >> 8) & 15, c1 = (o >> 4) & 15, f1 = o & 15;
    int n = c0 * 16 + c1;
    int f = f0 * 16 + f1;
    int i0 = idx[b * 4 + 0], i1 = idx[b * 4 + 1], i2 = idx[b * 4 + 2], i3 = idx[b * 4 + 3];
    int k = -1;
    if (n == i0) k = 0; else if (n == i1) k = 1; else if (n == i2) k = 2; else if (n == i3) k = 3;
    float r0, r1, r2, r3;
    if (k >= 0) {
        const float* fr = fine + ((size_t)(b * 4 + k)) * F_FINE + f;
        r0 = fr[0]; r1 = fr[1]; r2 = fr[2]; r3 = fr[3];
    } else {
        float base = coarse[(size_t)b * N_COARSE + n] - LOG_F;
        r0 = r1 = r2 = r3 = base;
    }
    size_t ob = (size_t)b * OUT_STRIDE + 1 + o;
    out[ob + 0] = r0; out[ob + 1] = r1; out[ob + 2] = r2; out[ob + 3] = r3;
}

extern "C" void kernel_launch(void* const* d_in, const int* in_sizes, int n_in,
                              void* d_out, int out_size, void* d_ws, size_t ws_size,
                              hipStream_t stream) {
    const float* x     = (const float*)d_in[0];
    const float* in_g  = (const float*)d_in[1];
    const float* in_b  = (const float*)d_in[2];
    const float* nop_w = (const float*)d_in[3];
    const float* nop_b = (const float*)d_in[4];
    const float* c_w1  = (const float*)d_in[5];
    const float* c_b1  = (const float*)d_in[6];
    const float* c_w2  = (const float*)d_in[7];
    const float* c_b2  = (const float*)d_in[8];
    const float* c_w3  = (const float*)d_in[9];
    const float* c_b3  = (const float*)d_in[10];
    const float* emb   = (const float*)d_in[11];
    const float* emb_g = (const float*)d_in[12];
    const float* emb_b = (const float*)d_in[13];
    const float* f_w1  = (const float*)d_in[14];
    const float* f_b1  = (const float*)d_in[15];
    const float* f_w2  = (const float*)d_in[16];
    const float* f_b2  = (const float*)d_in[17];
    const float* f_w3  = (const float*)d_in[18];
    const float* f_b3  = (const float*)d_in[19];

    float* ws = (float*)d_ws;
    float* xn      = ws;                         // 2048*512 f32
    float* h1      = xn + 1048576;               // 2048*512 f32
    float* h2      = h1 + 1048576;               // 2048*512 f32
    float* coarse  = h2 + 1048576;               // 2048*256 f32
    float* fine    = coarse + 524288;            // 8192*256 f32
    ushort_t* xn_bf  = (ushort_t*)(fine + 2097152);  // 2048*512 bf16
    ushort_t* e_bf   = xn_bf + 1048576;          // 8192*512
    ushort_t* fh1_bf = e_bf + 4194304;           // 8192*512
    ushort_t* fh2_bf = fh1_bf + 4194304;         // 8192*512
    ushort_t* wt1    = fh2_bf + 4194304;         // 512*1024
    ushort_t* wt2    = wt1 + 524288;             // 512*512
    ushort_t* wt3    = wt2 + 262144;             // 256*512
    int*   idxb   = (int*)(wt3 + 131072);        // 8192
    float* cvals  = (float*)(idxb + 8192);       // 8192

    float* out = (float*)d_out;

    // weight convert+transpose (bf16, N-major)
    convT_kernel<<<dim3(16, 32), 256, 0, stream>>>(f_w1, wt1, 1024, 512);
    convT_kernel<<<dim3(16, 16), 256, 0, stream>>>(f_w2, wt2, 512, 512);
    convT_kernel<<<dim3(8, 16), 256, 0, stream>>>(f_w3, wt3, 512, 256);

    // 1. LN + no_op
    ln_noop_kernel<<<BATCH, 256, 0, stream>>>(x, in_g, in_b, nop_w, nop_b, xn, xn_bf, out);
    // 2-4. coarse MLP (fp32 — top-k fidelity)
    gemm_kernel<true><<<dim3(8, 32), 256, 0, stream>>>(xn, c_w1, c_b1, h1, 2048, 512, 512);
    gemm_kernel<true><<<dim3(8, 32), 256, 0, stream>>>(h1, c_w2, c_b2, h2, 2048, 512, 512);
    gemm_kernel<false><<<dim3(4, 32), 256, 0, stream>>>(h2, c_w3, c_b3, coarse, 2048, 256, 512);
    // 5. top-4
    topk_kernel<<<BATCH, 64, 0, stream>>>(coarse, idxb, cvals);
    // 6. gather + LN emb rows -> bf16
    emb_ln_kernel<<<BATCH * K_TOP, 256, 0, stream>>>(emb, emb_g, emb_b, idxb, e_bf);
    // 7. fh1 = gelu(concat(xn,e) @ f_w1 + f_b1)   (bf16 MFMA, K=1024 concat)
    mfma_gemm_kernel<true, true, true><<<dim3(4, 64), 256, 0, stream>>>(
        xn_bf, e_bf, 512, wt1, f_b1, fh1_bf, 8192, 512, 1024);
    // 8. fh2 = gelu(fh1 @ f_w2 + f_b2)
    mfma_gemm_kernel<false, true, true><<<dim3(4, 64), 256, 0, stream>>>(
        fh1_bf, nullptr, 0, wt2, f_b2, fh2_bf, 8192, 512, 512);
    // 9. fine = fh2 @ f_w3 + f_b3  (f32 out)
    mfma_gemm_kernel<false, false, false><<<dim3(2, 64), 256, 0, stream>>>(
        fh2_bf, nullptr, 0, wt3, f_b3, fine, 8192, 256, 512);
    // 10. fine = cval + log_softmax(fine)
    logsm_kernel<<<BATCH * K_TOP, 64, 0, stream>>>(fine, cvals);
    // 11. scatter to permuted output
    scatter_kernel<<<dim3(64, BATCH), 256, 0, stream>>>(coarse, fine, idxb, out);
}

// Round 3
// 800.400 us; speedup vs baseline: 1.1746x; 1.0164x over previous
//
#include <hip/hip_runtime.h>
#include <math.h>

#define BATCH 2048
#define CH 512
#define N_COARSE 256
#define F_FINE 256
#define K_TOP 4
#define OUT_STRIDE 65537  // 1 + N*F

typedef unsigned short ushort_t;
typedef __bf16 bf16x8 __attribute__((ext_vector_type(8)));
typedef float f32x4 __attribute__((ext_vector_type(4)));

__device__ __forceinline__ float gelu_tanh(float x) {
    float x3 = x * x * x;
    float t = tanhf(0.7978845608028654f * (x + 0.044715f * x3));
    return 0.5f * x * (1.0f + t);
}

__device__ __forceinline__ ushort_t f2bf(float f) {
    unsigned u = __float_as_uint(f);
    unsigned r = (u + 0x7FFF + ((u >> 16) & 1)) >> 16;
    return (ushort_t)r;
}

// ---------------- LN(x) + no_op dot; writes fp32 xn and bf16 xn ----------------
__global__ __launch_bounds__(256) void ln_noop_kernel(
    const float* __restrict__ x, const float* __restrict__ g, const float* __restrict__ b,
    const float* __restrict__ nop_w, const float* __restrict__ nop_b,
    float* __restrict__ xn, ushort_t* __restrict__ xn_bf, float* __restrict__ out)
{
    int row = blockIdx.x;
    int t = threadIdx.x;
    int lane = t & 63, wave = t >> 6;
    const float* xr = x + (size_t)row * CH;
    float v0 = xr[t], v1 = xr[t + 256];
    float s = v0 + v1, ss = v0 * v0 + v1 * v1;
    #pragma unroll
    for (int off = 32; off; off >>= 1) { s += __shfl_xor(s, off); ss += __shfl_xor(ss, off); }
    __shared__ float red[8];
    if (lane == 0) { red[wave] = s; red[4 + wave] = ss; }
    __syncthreads();
    s = red[0] + red[1] + red[2] + red[3];
    ss = red[4] + red[5] + red[6] + red[7];
    float mean = s * (1.0f / CH);
    float var = ss * (1.0f / CH) - mean * mean;
    float rsq = rsqrtf(var + 1e-5f);
    float xn0 = (v0 - mean) * rsq * g[t] + b[t];
    float xn1 = (v1 - mean) * rsq * g[t + 256] + b[t + 256];
    float* xnr = xn + (size_t)row * CH;
    xnr[t] = xn0; xnr[t + 256] = xn1;
    ushort_t* xbr = xn_bf + (size_t)row * CH;
    xbr[t] = f2bf(xn0); xbr[t + 256] = f2bf(xn1);
    float d = xn0 * nop_w[t] + xn1 * nop_w[t + 256];
    #pragma unroll
    for (int off = 32; off; off >>= 1) d += __shfl_xor(d, off);
    __syncthreads();
    if (lane == 0) red[wave] = d;
    __syncthreads();
    if (t == 0) out[(size_t)row * OUT_STRIDE] = red[0] + red[1] + red[2] + red[3] + nop_b[0];
}

// ---------------- fused weight convert+transpose for all three fine weights ----------------
// blocks 0..511: f_w1 (1024x512); 512..767: f_w2 (512x512); 768..895: f_w3 (512x256)
__global__ __launch_bounds__(256) void convT_all_kernel(
    const float* __restrict__ w1, const float* __restrict__ w2, const float* __restrict__ w3,
    ushort_t* __restrict__ t1, ushort_t* __restrict__ t2, ushort_t* __restrict__ t3)
{
    __shared__ float s[32][33];
    int blk = blockIdx.x;
    const float* W; ushort_t* Wt; int Kd, Nd, gx, gy;
    if (blk < 512)      { W = w1; Wt = t1; Kd = 1024; Nd = 512; gx = blk & 15; gy = blk >> 4; }
    else if (blk < 768) { W = w2; Wt = t2; Kd = 512;  Nd = 512; gx = (blk - 512) & 15; gy = (blk - 512) >> 4; }
    else                { W = w3; Wt = t3; Kd = 512;  Nd = 256; gx = (blk - 768) & 7;  gy = (blk - 768) >> 3; }
    int tx = threadIdx.x & 31, ty = threadIdx.x >> 5;
    int n0 = gx * 32, k0 = gy * 32;
    #pragma unroll
    for (int i = 0; i < 4; ++i) {
        int r = ty + i * 8;
        s[r][tx] = W[(size_t)(k0 + r) * Nd + n0 + tx];
    }
    __syncthreads();
    #pragma unroll
    for (int i = 0; i < 4; ++i) {
        int r = ty + i * 8;
        Wt[(size_t)(n0 + r) * Kd + k0 + tx] = f2bf(s[tx][r]);
    }
}

// ---------------- fp32 tiled GEMM, 64x64 tile, BK=32, reg-prefetch + LDS dbuf ----------------
template<bool GELU>
__global__ __launch_bounds__(256) void gemm_kernel(
    const float* __restrict__ A, const float* __restrict__ W,
    const float* __restrict__ bias, float* __restrict__ Cmat, int Nd, int Kd)
{
    __shared__ float As[2][32][68];
    __shared__ float Ws[2][32][68];
    int t = threadIdx.x;
    int tx = t & 15, ty = t >> 4;
    int n0 = blockIdx.x * 64, m0 = blockIdx.y * 64;

    float4 aR[2], wR[2];
    float acc[4][4] = {};

    auto loadAB = [&](int k0) {
        #pragma unroll
        for (int i = 0; i < 2; ++i) {
            int c = i * 256 + t;
            aR[i] = *(const float4*)&A[(size_t)(m0 + (c >> 3)) * Kd + k0 + (c & 7) * 4];
        }
        #pragma unroll
        for (int i = 0; i < 2; ++i) {
            int c = i * 256 + t;
            wR[i] = *(const float4*)&W[(size_t)(k0 + (c >> 4)) * Nd + n0 + (c & 15) * 4];
        }
    };
    auto storeAB = [&](int p) {
        #pragma unroll
        for (int i = 0; i < 2; ++i) {
            int c = i * 256 + t, r = c >> 3, kq = (c & 7) * 4;
            As[p][kq + 0][r] = aR[i].x; As[p][kq + 1][r] = aR[i].y;
            As[p][kq + 2][r] = aR[i].z; As[p][kq + 3][r] = aR[i].w;
        }
        #pragma unroll
        for (int i = 0; i < 2; ++i) {
            int c = i * 256 + t;
            *(float4*)&Ws[p][c >> 4][(c & 15) * 4] = wR[i];
        }
    };

    loadAB(0);
    storeAB(0);
    int steps = Kd >> 5;
    int p = 0;
    for (int s = 0; s < steps; ++s) {
        __syncthreads();
        if (s + 1 < steps) loadAB((s + 1) * 32);
        #pragma unroll
        for (int kk = 0; kk < 32; ++kk) {
            float4 a = *(const float4*)&As[p][kk][ty * 4];
            float4 w = *(const float4*)&Ws[p][kk][tx * 4];
            acc[0][0] += a.x * w.x; acc[0][1] += a.x * w.y; acc[0][2] += a.x * w.z; acc[0][3] += a.x * w.w;
            acc[1][0] += a.y * w.x; acc[1][1] += a.y * w.y; acc[1][2] += a.y * w.z; acc[1][3] += a.y * w.w;
            acc[2][0] += a.z * w.x; acc[2][1] += a.z * w.y; acc[2][2] += a.z * w.z; acc[2][3] += a.z * w.w;
            acc[3][0] += a.w * w.x; acc[3][1] += a.w * w.y; acc[3][2] += a.w * w.z; acc[3][3] += a.w * w.w;
        }
        if (s + 1 < steps) storeAB(p ^ 1);
        p ^= 1;
    }

    #pragma unroll
    for (int i = 0; i < 4; ++i) {
        int gm = m0 + ty * 4 + i;
        int gn0 = n0 + tx * 4;
        float4 o;
        float* po = &o.x;
        #pragma unroll
        for (int j = 0; j < 4; ++j) {
            float v = acc[i][j] + bias[gn0 + j];
            if (GELU) v = gelu_tanh(v);
            po[j] = v;
        }
        *(float4*)&Cmat[(size_t)gm * Nd + gn0] = o;
    }
}

// ---------------- bf16 MFMA GEMM, MTxNT tile, BK=32, reg-prefetch + LDS dbuf ----------------
// Wt is (Nd x Ktot) bf16 row-major. CONCAT: k<K1 -> A1[row>>2] (stride K1), else A2[row].
template<int MT, int NT, bool CONCAT, bool GELU, bool OUT_BF16>
__global__ __launch_bounds__(256) void mfma_gemm_kernel(
    const ushort_t* __restrict__ A1, const ushort_t* __restrict__ A2, int K1,
    const ushort_t* __restrict__ Wt, const float* __restrict__ bias,
    void* __restrict__ Cout, int Nd, int Ktot)
{
    constexpr int AI = MT * 4 / 256, BI = NT * 4 / 256;
    constexpr int FI = MT / 32, FJ = NT / 32;
    __shared__ ushort_t As[2][MT * 32];
    __shared__ ushort_t Bs[2][NT * 32];
    int t = threadIdx.x;
    int n0 = blockIdx.x * NT, m0 = blockIdx.y * MT;
    int wave = t >> 6, lane = t & 63;
    int wm = (wave & 1) * (MT / 2), wn = (wave >> 1) * (NT / 2);
    int lr = lane & 15, quad = lane >> 4;

    f32x4 acc[FI][FJ] = {};
    float4 aReg[AI], bReg[BI];

    auto loadAB = [&](int k0) {
        #pragma unroll
        for (int i = 0; i < AI; ++i) {
            int c = i * 256 + t, r = c >> 2, q = (c & 3) * 8;
            int gr = m0 + r;
            const ushort_t* ap;
            if (CONCAT) ap = (k0 < K1) ? A1 + (size_t)(gr >> 2) * K1 + k0 + q
                                       : A2 + (size_t)gr * (Ktot - K1) + (k0 - K1) + q;
            else        ap = A1 + (size_t)gr * Ktot + k0 + q;
            aReg[i] = *(const float4*)ap;
        }
        #pragma unroll
        for (int i = 0; i < BI; ++i) {
            int c = i * 256 + t, r = c >> 2, q = (c & 3) * 8;
            bReg[i] = *(const float4*)(Wt + (size_t)(n0 + r) * Ktot + k0 + q);
        }
    };
    auto storeAB = [&](int p) {
        #pragma unroll
        for (int i = 0; i < AI; ++i) { int c = i * 256 + t; *(float4*)&As[p][c * 8] = aReg[i]; }
        #pragma unroll
        for (int i = 0; i < BI; ++i) { int c = i * 256 + t; *(float4*)&Bs[p][c * 8] = bReg[i]; }
    };

    loadAB(0);
    storeAB(0);
    int steps = Ktot >> 5;
    int p = 0;
    for (int s = 0; s < steps; ++s) {
        __syncthreads();
        if (s + 1 < steps) loadAB((s + 1) * 32);
        bf16x8 af[FI], bfr[FJ];
        #pragma unroll
        for (int i = 0; i < FI; ++i)
            af[i] = *(const bf16x8*)&As[p][(wm + i * 16 + lr) * 32 + quad * 8];
        #pragma unroll
        for (int j = 0; j < FJ; ++j)
            bfr[j] = *(const bf16x8*)&Bs[p][(wn + j * 16 + lr) * 32 + quad * 8];
        #pragma unroll
        for (int i = 0; i < FI; ++i)
            #pragma unroll
            for (int j = 0; j < FJ; ++j)
                acc[i][j] = __builtin_amdgcn_mfma_f32_16x16x32_bf16(af[i], bfr[j], acc[i][j], 0, 0, 0);
        if (s + 1 < steps) storeAB(p ^ 1);
        p ^= 1;
    }

    #pragma unroll
    for (int j = 0; j < FJ; ++j) {
        int col = n0 + wn + j * 16 + lr;
        float bv = bias[col];
        #pragma unroll
        for (int i = 0; i < FI; ++i) {
            #pragma unroll
            for (int r = 0; r < 4; ++r) {
                int row = m0 + wm + i * 16 + quad * 4 + r;
                float val = acc[i][j][r] + bv;
                if (GELU) val = gelu_tanh(val);
                if (OUT_BF16)
                    ((ushort_t*)Cout)[(size_t)row * Nd + col] = f2bf(val);
                else
                    ((float*)Cout)[(size_t)row * Nd + col] = val;
            }
        }
    }
}

// ---------------- fused: top-4 per row + gather+LN of the 4 emb rows -> bf16 ----------------
__global__ __launch_bounds__(256) void topk_embln_kernel(
    const float* __restrict__ coarse, const float* __restrict__ emb,
    const float* __restrict__ g, const float* __restrict__ b,
    int* __restrict__ idx, float* __restrict__ cvals, ushort_t* __restrict__ e_bf)
{
    int brow = blockIdx.x;
    int t = threadIdx.x;
    int wave = t >> 6, lane = t & 63;
    __shared__ int sidx[4];

    if (wave == 0) {
        const float* cr = coarse + (size_t)brow * N_COARSE;
        float v[4]; int id[4];
        #pragma unroll
        for (int j = 0; j < 4; ++j) { v[j] = cr[lane + 64 * j]; id[j] = lane + 64 * j; }
        #pragma unroll
        for (int r = 0; r < K_TOP; ++r) {
            float bv = v[0]; int bi = id[0];
            #pragma unroll
            for (int j = 1; j < 4; ++j)
                if (v[j] > bv || (v[j] == bv && id[j] < bi)) { bv = v[j]; bi = id[j]; }
            #pragma unroll
            for (int off = 32; off; off >>= 1) {
                float ov = __shfl_xor(bv, off); int oi = __shfl_xor(bi, off);
                if (ov > bv || (ov == bv && oi < bi)) { bv = ov; bi = oi; }
            }
            if ((bi & 63) == lane) v[bi >> 6] = -INFINITY;
            if (lane == 0) {
                sidx[r] = bi;
                idx[brow * K_TOP + r] = bi;
                cvals[brow * K_TOP + r] = bv;
            }
        }
    }
    __syncthreads();

    int n = sidx[wave];
    const float* er = emb + (size_t)n * CH + lane * 8;
    float4 u0 = *(const float4*)er;
    float4 u1 = *(const float4*)(er + 4);
    float s  = u0.x + u0.y + u0.z + u0.w + u1.x + u1.y + u1.z + u1.w;
    float ss = u0.x * u0.x + u0.y * u0.y + u0.z * u0.z + u0.w * u0.w
             + u1.x * u1.x + u1.y * u1.y + u1.z * u1.z + u1.w * u1.w;
    #pragma unroll
    for (int off = 32; off; off >>= 1) { s += __shfl_xor(s, off); ss += __shfl_xor(ss, off); }
    float mean = s * (1.0f / CH);
    float var = ss * (1.0f / CH) - mean * mean;
    float rsq = rsqrtf(var + 1e-5f);
    float4 g0 = *(const float4*)(g + lane * 8), g1 = *(const float4*)(g + lane * 8 + 4);
    float4 b0 = *(const float4*)(b + lane * 8), b1 = *(const float4*)(b + lane * 8 + 4);
    uint4 pk;
    pk.x = (unsigned)f2bf((u0.x - mean) * rsq * g0.x + b0.x) |
           ((unsigned)f2bf((u0.y - mean) * rsq * g0.y + b0.y) << 16);
    pk.y = (unsigned)f2bf((u0.z - mean) * rsq * g0.z + b0.z) |
           ((unsigned)f2bf((u0.w - mean) * rsq * g0.w + b0.w) << 16);
    pk.z = (unsigned)f2bf((u1.x - mean) * rsq * g1.x + b1.x) |
           ((unsigned)f2bf((u1.y - mean) * rsq * g1.y + b1.y) << 16);
    pk.w = (unsigned)f2bf((u1.z - mean) * rsq * g1.z + b1.z) |
           ((unsigned)f2bf((u1.w - mean) * rsq * g1.w + b1.w) << 16);
    *(uint4*)(e_bf + (size_t)(brow * K_TOP + wave) * CH + lane * 8) = pk;
}

// ---------------- log_softmax + coarse val (in place) ----------------
__global__ __launch_bounds__(64) void logsm_kernel(
    float* __restrict__ fine, const float* __restrict__ cvals)
{
    int row = blockIdx.x;
    int lane = threadIdx.x;
    float* fr = fine + (size_t)row * F_FINE;
    float v[4];
    #pragma unroll
    for (int j = 0; j < 4; ++j) v[j] = fr[lane + 64 * j];
    float mx = fmaxf(fmaxf(v[0], v[1]), fmaxf(v[2], v[3]));
    #pragma unroll
    for (int off = 32; off; off >>= 1) mx = fmaxf(mx, __shfl_xor(mx, off));
    float se = 0.f;
    #pragma unroll
    for (int j = 0; j < 4; ++j) se += expf(v[j] - mx);
    #pragma unroll
    for (int off = 32; off; off >>= 1) se += __shfl_xor(se, off);
    float addc = cvals[row] - mx - logf(se);
    #pragma unroll
    for (int j = 0; j < 4; ++j) fr[lane + 64 * j] = v[j] + addc;
}

// ---------------- final scatter into permuted dense output ----------------
__global__ __launch_bounds__(256) void scatter_kernel(
    const float* __restrict__ coarse, const float* __restrict__ fine,
    const int* __restrict__ idx, float* __restrict__ out)
{
    const float LOG_F = 5.545177444479562f;
    int b = blockIdx.y;
    int o = (blockIdx.x * 256 + threadIdx.x) * 4;
    int c0 = o >> 12, f0 = (o >> 8) & 15, c1 = (o >> 4) & 15, f1 = o & 15;
    int n = c0 * 16 + c1;
    int f = f0 * 16 + f1;
    int i0 = idx[b * 4 + 0], i1 = idx[b * 4 + 1], i2 = idx[b * 4 + 2], i3 = idx[b * 4 + 3];
    int k = -1;
    if (n == i0) k = 0; else if (n == i1) k = 1; else if (n == i2) k = 2; else if (n == i3) k = 3;
    float r0, r1, r2, r3;
    if (k >= 0) {
        const float* fr = fine + ((size_t)(b * 4 + k)) * F_FINE + f;
        r0 = fr[0]; r1 = fr[1]; r2 = fr[2]; r3 = fr[3];
    } else {
        float base = coarse[(size_t)b * N_COARSE + n] - LOG_F;
        r0 = r1 = r2 = r3 = base;
    }
    size_t ob = (size_t)b * OUT_STRIDE + 1 + o;
    __builtin_nontemporal_store(r0, &out[ob + 0]);
    __builtin_nontemporal_store(r1, &out[ob + 1]);
    __builtin_nontemporal_store(r2, &out[ob + 2]);
    __builtin_nontemporal_store(r3, &out[ob + 3]);
}

extern "C" void kernel_launch(void* const* d_in, const int* in_sizes, int n_in,
                              void* d_out, int out_size, void* d_ws, size_t ws_size,
                              hipStream_t stream) {
    const float* x     = (const float*)d_in[0];
    const float* in_g  = (const float*)d_in[1];
    const float* in_b  = (const float*)d_in[2];
    const float* nop_w = (const float*)d_in[3];
    const float* nop_b = (const float*)d_in[4];
    const float* c_w1  = (const float*)d_in[5];
    const float* c_b1  = (const float*)d_in[6];
    const float* c_w2  = (const float*)d_in[7];
    const float* c_b2  = (const float*)d_in[8];
    const float* c_w3  = (const float*)d_in[9];
    const float* c_b3  = (const float*)d_in[10];
    const float* emb   = (const float*)d_in[11];
    const float* emb_g = (const float*)d_in[12];
    const float* emb_b = (const float*)d_in[13];
    const float* f_w1  = (const float*)d_in[14];
    const float* f_b1  = (const float*)d_in[15];
    const float* f_w2  = (const float*)d_in[16];
    const float* f_b2  = (const float*)d_in[17];
    const float* f_w3  = (const float*)d_in[18];
    const float* f_b3  = (const float*)d_in[19];

    float* ws = (float*)d_ws;
    float* xn      = ws;                         // 2048*512 f32
    float* h1      = xn + 1048576;               // 2048*512 f32
    float* h2      = h1 + 1048576;               // 2048*512 f32
    float* coarse  = h2 + 1048576;               // 2048*256 f32
    float* fine    = coarse + 524288;            // 8192*256 f32
    ushort_t* xn_bf  = (ushort_t*)(fine + 2097152);  // 2048*512 bf16
    ushort_t* e_bf   = xn_bf + 1048576;          // 8192*512
    ushort_t* fh1_bf = e_bf + 4194304;           // 8192*512
    ushort_t* fh2_bf = fh1_bf + 4194304;         // 8192*512
    ushort_t* wt1    = fh2_bf + 4194304;         // 512*1024
    ushort_t* wt2    = wt1 + 524288;             // 512*512
    ushort_t* wt3    = wt2 + 262144;             // 256*512
    int*   idxb   = (int*)(wt3 + 131072);        // 8192
    float* cvals  = (float*)(idxb + 8192);       // 8192

    float* out = (float*)d_out;

    // weight convert+transpose (all three, one launch)
    convT_all_kernel<<<896, 256, 0, stream>>>(f_w1, f_w2, f_w3, wt1, wt2, wt3);
    // 1. LN + no_op
    ln_noop_kernel<<<BATCH, 256, 0, stream>>>(x, in_g, in_b, nop_w, nop_b, xn, xn_bf, out);
    // 2-4. coarse MLP (fp32 — top-k fidelity), pipelined
    gemm_kernel<true><<<dim3(8, 32), 256, 0, stream>>>(xn, c_w1, c_b1, h1, 512, 512);
    gemm_kernel<true><<<dim3(8, 32), 256, 0, stream>>>(h1, c_w2, c_b2, h2, 512, 512);
    gemm_kernel<false><<<dim3(4, 32), 256, 0, stream>>>(h2, c_w3, c_b3, coarse, 256, 512);
    // 5. fused top-4 + emb gather+LN -> bf16
    topk_embln_kernel<<<BATCH, 256, 0, stream>>>(coarse, emb, emb_g, emb_b, idxb, cvals, e_bf);
    // 6. fh1 = gelu(concat(xn,e) @ f_w1 + f_b1)
    mfma_gemm_kernel<128, 128, true, true, true><<<dim3(4, 64), 256, 0, stream>>>(
        xn_bf, e_bf, 512, wt1, f_b1, fh1_bf, 512, 1024);
    // 7. fh2 = gelu(fh1 @ f_w2 + f_b2)
    mfma_gemm_kernel<128, 128, false, true, true><<<dim3(4, 64), 256, 0, stream>>>(
        fh1_bf, nullptr, 0, wt2, f_b2, fh2_bf, 512, 512);
    // 8. fine = fh2 @ f_w3 + f_b3  (f32 out), MT=64 keeps grid at 256 blocks
    mfma_gemm_kernel<64, 128, false, false, false><<<dim3(2, 128), 256, 0, stream>>>(
        fh2_bf, nullptr, 0, wt3, f_b3, fine, 256, 512);
    // 9. fine = cval + log_softmax(fine)
    logsm_kernel<<<BATCH * K_TOP, 64, 0, stream>>>(fine, cvals);
    // 10. scatter to permuted output
    scatter_kernel<<<dim3(64, BATCH), 256, 0, stream>>>(coarse, fine, idxb, out);
}

// Round 5
// 777.445 us; speedup vs baseline: 1.2093x; 1.0295x over previous
//
#include <hip/hip_runtime.h>
#include <math.h>

#define BATCH 2048
#define CH 512
#define N_COARSE 256
#define F_FINE 256
#define K_TOP 4
#define OUT_STRIDE 65537  // 1 + N*F

typedef unsigned short ushort_t;
typedef __bf16 bf16x8 __attribute__((ext_vector_type(8)));
typedef float f32x4 __attribute__((ext_vector_type(4)));

__device__ __forceinline__ float gelu_tanh(float x) {
    float x3 = x * x * x;
    float t = tanhf(0.7978845608028654f * (x + 0.044715f * x3));
    return 0.5f * x * (1.0f + t);
}

__device__ __forceinline__ ushort_t f2bf(float f) {
    unsigned u = __float_as_uint(f);
    unsigned r = (u + 0x7FFF + ((u >> 16) & 1)) >> 16;
    return (ushort_t)r;
}

// ---------------- fused prep: weight convT (blocks 0..895) + LN+no_op (blocks 896..2943) ----
__global__ __launch_bounds__(256) void prep_kernel(
    const float* __restrict__ w1, const float* __restrict__ w2, const float* __restrict__ w3,
    ushort_t* __restrict__ t1, ushort_t* __restrict__ t2, ushort_t* __restrict__ t3,
    const float* __restrict__ x, const float* __restrict__ g, const float* __restrict__ b,
    const float* __restrict__ nop_w, const float* __restrict__ nop_b,
    float* __restrict__ xn, ushort_t* __restrict__ xn_bf, float* __restrict__ out)
{
    int blk = blockIdx.x;
    int t = threadIdx.x;
    if (blk < 896) {
        __shared__ float s[32][33];
        const float* W; ushort_t* Wt; int Kd, Nd, gx, gy;
        if (blk < 512)      { W = w1; Wt = t1; Kd = 1024; Nd = 512; gx = blk & 15; gy = blk >> 4; }
        else if (blk < 768) { W = w2; Wt = t2; Kd = 512;  Nd = 512; gx = (blk - 512) & 15; gy = (blk - 512) >> 4; }
        else                { W = w3; Wt = t3; Kd = 512;  Nd = 256; gx = (blk - 768) & 7;  gy = (blk - 768) >> 3; }
        int tx = t & 31, ty = t >> 5;
        int n0 = gx * 32, k0 = gy * 32;
        #pragma unroll
        for (int i = 0; i < 4; ++i) {
            int r = ty + i * 8;
            s[r][tx] = W[(size_t)(k0 + r) * Nd + n0 + tx];
        }
        __syncthreads();
        #pragma unroll
        for (int i = 0; i < 4; ++i) {
            int r = ty + i * 8;
            Wt[(size_t)(n0 + r) * Kd + k0 + tx] = f2bf(s[tx][r]);
        }
    } else {
        int row = blk - 896;
        int lane = t & 63, wave = t >> 6;
        const float* xr = x + (size_t)row * CH;
        float v0 = xr[t], v1 = xr[t + 256];
        float s = v0 + v1, ss = v0 * v0 + v1 * v1;
        #pragma unroll
        for (int off = 32; off; off >>= 1) { s += __shfl_xor(s, off); ss += __shfl_xor(ss, off); }
        __shared__ float red[8];
        if (lane == 0) { red[wave] = s; red[4 + wave] = ss; }
        __syncthreads();
        s = red[0] + red[1] + red[2] + red[3];
        ss = red[4] + red[5] + red[6] + red[7];
        float mean = s * (1.0f / CH);
        float var = ss * (1.0f / CH) - mean * mean;
        float rsq = rsqrtf(var + 1e-5f);
        float xn0 = (v0 - mean) * rsq * g[t] + b[t];
        float xn1 = (v1 - mean) * rsq * g[t + 256] + b[t + 256];
        float* xnr = xn + (size_t)row * CH;
        xnr[t] = xn0; xnr[t + 256] = xn1;
        ushort_t* xbr = xn_bf + (size_t)row * CH;
        xbr[t] = f2bf(xn0); xbr[t + 256] = f2bf(xn1);
        float d = xn0 * nop_w[t] + xn1 * nop_w[t + 256];
        #pragma unroll
        for (int off = 32; off; off >>= 1) d += __shfl_xor(d, off);
        __syncthreads();
        if (lane == 0) red[wave] = d;
        __syncthreads();
        if (t == 0) out[(size_t)row * OUT_STRIDE] = red[0] + red[1] + red[2] + red[3] + nop_b[0];
    }
}

// ---------------- fp32 tiled GEMM, 64x32 tile, BK=32, dbuf, 2 blocks/CU ----------------
template<bool GELU>
__global__ __launch_bounds__(256) void gemm_kernel(
    const float* __restrict__ A, const float* __restrict__ W,
    const float* __restrict__ bias, float* __restrict__ Cmat, int Nd, int Kd)
{
    __shared__ float As[2][32][68];   // [k][m], padded
    __shared__ float Ws[2][32][36];   // [k][n], padded
    int t = threadIdx.x;
    int tx = t & 7, ty = t >> 3;      // tx: 8 col-groups x4; ty: 32 row-groups x2
    int n0 = blockIdx.x * 32, m0 = blockIdx.y * 64;

    float4 aR[2]; float4 wR;
    float acc[2][4] = {};

    auto loadAB = [&](int k0) {
        #pragma unroll
        for (int i = 0; i < 2; ++i) {
            int c = i * 256 + t;
            aR[i] = *(const float4*)&A[(size_t)(m0 + (c >> 3)) * Kd + k0 + (c & 7) * 4];
        }
        wR = *(const float4*)&W[(size_t)(k0 + (t >> 3)) * Nd + n0 + (t & 7) * 4];
    };
    auto storeAB = [&](int p) {
        #pragma unroll
        for (int i = 0; i < 2; ++i) {
            int c = i * 256 + t, r = c >> 3, kq = (c & 7) * 4;
            As[p][kq + 0][r] = aR[i].x; As[p][kq + 1][r] = aR[i].y;
            As[p][kq + 2][r] = aR[i].z; As[p][kq + 3][r] = aR[i].w;
        }
        *(float4*)&Ws[p][t >> 3][(t & 7) * 4] = wR;
    };

    loadAB(0);
    storeAB(0);
    int steps = Kd >> 5;
    int p = 0;
    for (int s = 0; s < steps; ++s) {
        __syncthreads();
        if (s + 1 < steps) loadAB((s + 1) * 32);
        #pragma unroll
        for (int kk = 0; kk < 32; ++kk) {
            float2 a = *(const float2*)&As[p][kk][ty * 2];
            float4 w = *(const float4*)&Ws[p][kk][tx * 4];
            acc[0][0] += a.x * w.x; acc[0][1] += a.x * w.y; acc[0][2] += a.x * w.z; acc[0][3] += a.x * w.w;
            acc[1][0] += a.y * w.x; acc[1][1] += a.y * w.y; acc[1][2] += a.y * w.z; acc[1][3] += a.y * w.w;
        }
        if (s + 1 < steps) storeAB(p ^ 1);
        p ^= 1;
    }

    #pragma unroll
    for (int i = 0; i < 2; ++i) {
        int gm = m0 + ty * 2 + i;
        int gn0 = n0 + tx * 4;
        float4 o;
        float* po = &o.x;
        #pragma unroll
        for (int j = 0; j < 4; ++j) {
            float v = acc[i][j] + bias[gn0 + j];
            if (GELU) v = gelu_tanh(v);
            po[j] = v;
        }
        *(float4*)&Cmat[(size_t)gm * Nd + gn0] = o;
    }
}

// ---------------- bf16 MFMA GEMM, MTxNT tile, BK=32, dbuf; optional fused logsm epilogue ----
// Wt is (Nd x Ktot) bf16 row-major. CONCAT: k<K1 -> A1[row>>2] (stride K1), else A2[row].
// LOGSM: Nd == NT == 256, Cout f32; writes cvals[row] + log_softmax(row) in fp32.
template<int MT, int NT, bool CONCAT, bool GELU, bool OUT_BF16, bool LOGSM>
__global__ __launch_bounds__(256) void mfma_gemm_kernel(
    const ushort_t* __restrict__ A1, const ushort_t* __restrict__ A2, int K1,
    const ushort_t* __restrict__ Wt, const float* __restrict__ bias,
    const float* __restrict__ cvals, void* __restrict__ Cout, int Nd, int Ktot)
{
    constexpr int AI = MT / 64, BI = NT / 64;
    constexpr int FI = MT / 32, FJ = NT / 32;
    __shared__ ushort_t As[2][MT * 32];
    __shared__ ushort_t Bs[2][NT * 32];
    __shared__ float mxs[64][2];
    __shared__ float ses[64][2];
    int t = threadIdx.x;
    int n0 = blockIdx.x * NT, m0 = blockIdx.y * MT;
    int wave = t >> 6, lane = t & 63;
    int wm = (wave & 1) * (MT / 2), wn = (wave >> 1) * (NT / 2);
    int lr = lane & 15, quad = lane >> 4;

    f32x4 acc[FI][FJ] = {};
    float4 aReg[AI], bReg[BI];

    auto loadAB = [&](int k0) {
        #pragma unroll
        for (int i = 0; i < AI; ++i) {
            int c = i * 256 + t, r = c >> 2, q = (c & 3) * 8;
            int gr = m0 + r;
            const ushort_t* ap;
            if (CONCAT) ap = (k0 < K1) ? A1 + (size_t)(gr >> 2) * K1 + k0 + q
                                       : A2 + (size_t)gr * (Ktot - K1) + (k0 - K1) + q;
            else        ap = A1 + (size_t)gr * Ktot + k0 + q;
            aReg[i] = *(const float4*)ap;
        }
        #pragma unroll
        for (int i = 0; i < BI; ++i) {
            int c = i * 256 + t, r = c >> 2, q = (c & 3) * 8;
            bReg[i] = *(const float4*)(Wt + (size_t)(n0 + r) * Ktot + k0 + q);
        }
    };
    auto storeAB = [&](int p) {
        #pragma unroll
        for (int i = 0; i < AI; ++i) { int c = i * 256 + t; *(float4*)&As[p][c * 8] = aReg[i]; }
        #pragma unroll
        for (int i = 0; i < BI; ++i) { int c = i * 256 + t; *(float4*)&Bs[p][c * 8] = bReg[i]; }
    };

    loadAB(0);
    storeAB(0);
    int steps = Ktot >> 5;
    int p = 0;
    for (int s = 0; s < steps; ++s) {
        __syncthreads();
        if (s + 1 < steps) loadAB((s + 1) * 32);
        bf16x8 af[FI], bfr[FJ];
        #pragma unroll
        for (int i = 0; i < FI; ++i)
            af[i] = *(const bf16x8*)&As[p][(wm + i * 16 + lr) * 32 + quad * 8];
        #pragma unroll
        for (int j = 0; j < FJ; ++j)
            bfr[j] = *(const bf16x8*)&Bs[p][(wn + j * 16 + lr) * 32 + quad * 8];
        #pragma unroll
        for (int i = 0; i < FI; ++i)
            #pragma unroll
            for (int j = 0; j < FJ; ++j)
                acc[i][j] = __builtin_amdgcn_mfma_f32_16x16x32_bf16(af[i], bfr[j], acc[i][j], 0, 0, 0);
        if (s + 1 < steps) storeAB(p ^ 1);
        p ^= 1;
    }

    if (LOGSM) {
        float bv[FJ];
        #pragma unroll
        for (int j = 0; j < FJ; ++j) bv[j] = bias[wn + j * 16 + lr];
        int half = wave >> 1;
        float rmx[FI][4];
        #pragma unroll
        for (int i = 0; i < FI; ++i)
            #pragma unroll
            for (int r = 0; r < 4; ++r) {
                float m = -1e30f;
                #pragma unroll
                for (int j = 0; j < FJ; ++j) m = fmaxf(m, acc[i][j][r] + bv[j]);
                #pragma unroll
                for (int mk = 1; mk < 16; mk <<= 1) m = fmaxf(m, __shfl_xor(m, mk));
                if (lr == 0) mxs[wm + i * 16 + quad * 4 + r][half] = m;
            }
        __syncthreads();
        #pragma unroll
        for (int i = 0; i < FI; ++i)
            #pragma unroll
            for (int r = 0; r < 4; ++r) {
                int rl = wm + i * 16 + quad * 4 + r;
                rmx[i][r] = fmaxf(mxs[rl][0], mxs[rl][1]);
            }
        #pragma unroll
        for (int i = 0; i < FI; ++i)
            #pragma unroll
            for (int r = 0; r < 4; ++r) {
                float s = 0.f;
                #pragma unroll
                for (int j = 0; j < FJ; ++j) s += expf(acc[i][j][r] + bv[j] - rmx[i][r]);
                #pragma unroll
                for (int mk = 1; mk < 16; mk <<= 1) s += __shfl_xor(s, mk);
                if (lr == 0) ses[wm + i * 16 + quad * 4 + r][half] = s;
            }
        __syncthreads();
        float* outp = (float*)Cout;
        #pragma unroll
        for (int i = 0; i < FI; ++i)
            #pragma unroll
            for (int r = 0; r < 4; ++r) {
                int rl = wm + i * 16 + quad * 4 + r;
                float se = ses[rl][0] + ses[rl][1];
                float addc = cvals[m0 + rl] - rmx[i][r] - logf(se);
                #pragma unroll
                for (int j = 0; j < FJ; ++j)
                    outp[(size_t)(m0 + rl) * Nd + wn + j * 16 + lr] = acc[i][j][r] + bv[j] + addc;
            }
    } else {
        #pragma unroll
        for (int j = 0; j < FJ; ++j) {
            int col = n0 + wn + j * 16 + lr;
            float bvv = bias[col];
            #pragma unroll
            for (int i = 0; i < FI; ++i) {
                #pragma unroll
                for (int r = 0; r < 4; ++r) {
                    int row = m0 + wm + i * 16 + quad * 4 + r;
                    float val = acc[i][j][r] + bvv;
                    if (GELU) val = gelu_tanh(val);
                    if (OUT_BF16)
                        ((ushort_t*)Cout)[(size_t)row * Nd + col] = f2bf(val);
                    else
                        ((float*)Cout)[(size_t)row * Nd + col] = val;
                }
            }
        }
    }
}

// ---------------- fused: top-4 per row + gather+LN of the 4 emb rows -> bf16 ----------------
__global__ __launch_bounds__(256) void topk_embln_kernel(
    const float* __restrict__ coarse, const float* __restrict__ emb,
    const float* __restrict__ g, const float* __restrict__ b,
    int* __restrict__ idx, float* __restrict__ cvals, ushort_t* __restrict__ e_bf)
{
    int brow = blockIdx.x;
    int t = threadIdx.x;
    int wave = t >> 6, lane = t & 63;
    __shared__ int sidx[4];

    if (wave == 0) {
        const float* cr = coarse + (size_t)brow * N_COARSE;
        float v[4]; int id[4];
        #pragma unroll
        for (int j = 0; j < 4; ++j) { v[j] = cr[lane + 64 * j]; id[j] = lane + 64 * j; }
        #pragma unroll
        for (int r = 0; r < K_TOP; ++r) {
            float bv = v[0]; int bi = id[0];
            #pragma unroll
            for (int j = 1; j < 4; ++j)
                if (v[j] > bv || (v[j] == bv && id[j] < bi)) { bv = v[j]; bi = id[j]; }
            #pragma unroll
            for (int off = 32; off; off >>= 1) {
                float ov = __shfl_xor(bv, off); int oi = __shfl_xor(bi, off);
                if (ov > bv || (ov == bv && oi < bi)) { bv = ov; bi = oi; }
            }
            if ((bi & 63) == lane) v[bi >> 6] = -INFINITY;
            if (lane == 0) {
                sidx[r] = bi;
                idx[brow * K_TOP + r] = bi;
                cvals[brow * K_TOP + r] = bv;
            }
        }
    }
    __syncthreads();

    int n = sidx[wave];
    const float* er = emb + (size_t)n * CH + lane * 8;
    float4 u0 = *(const float4*)er;
    float4 u1 = *(const float4*)(er + 4);
    float s  = u0.x + u0.y + u0.z + u0.w + u1.x + u1.y + u1.z + u1.w;
    float ss = u0.x * u0.x + u0.y * u0.y + u0.z * u0.z + u0.w * u0.w
             + u1.x * u1.x + u1.y * u1.y + u1.z * u1.z + u1.w * u1.w;
    #pragma unroll
    for (int off = 32; off; off >>= 1) { s += __shfl_xor(s, off); ss += __shfl_xor(ss, off); }
    float mean = s * (1.0f / CH);
    float var = ss * (1.0f / CH) - mean * mean;
    float rsq = rsqrtf(var + 1e-5f);
    float4 g0 = *(const float4*)(g + lane * 8), g1 = *(const float4*)(g + lane * 8 + 4);
    float4 b0 = *(const float4*)(b + lane * 8), b1 = *(const float4*)(b + lane * 8 + 4);
    uint4 pk;
    pk.x = (unsigned)f2bf((u0.x - mean) * rsq * g0.x + b0.x) |
           ((unsigned)f2bf((u0.y - mean) * rsq * g0.y + b0.y) << 16);
    pk.y = (unsigned)f2bf((u0.z - mean) * rsq * g0.z + b0.z) |
           ((unsigned)f2bf((u0.w - mean) * rsq * g0.w + b0.w) << 16);
    pk.z = (unsigned)f2bf((u1.x - mean) * rsq * g1.x + b1.x) |
           ((unsigned)f2bf((u1.y - mean) * rsq * g1.y + b1.y) << 16);
    pk.w = (unsigned)f2bf((u1.z - mean) * rsq * g1.z + b1.z) |
           ((unsigned)f2bf((u1.w - mean) * rsq * g1.w + b1.w) << 16);
    *(uint4*)(e_bf + (size_t)(brow * K_TOP + wave) * CH + lane * 8) = pk;
}

// ---------------- final scatter into permuted dense output ----------------
// grid (16, BATCH): block covers 4096 consecutive output elems; q-loop 4 x 1024.
__global__ __launch_bounds__(256) void scatter_kernel(
    const float* __restrict__ coarse, const float* __restrict__ fine,
    const int* __restrict__ idx, float* __restrict__ out)
{
    const float LOG_F = 5.545177444479562f;
    int b = blockIdx.y;
    __shared__ int sidx[4];
    if (threadIdx.x < 4) sidx[threadIdx.x] = idx[b * 4 + threadIdx.x];
    __syncthreads();
    int i0 = sidx[0], i1 = sidx[1], i2 = sidx[2], i3 = sidx[3];
    size_t rowb = (size_t)b * OUT_STRIDE + 1;
    #pragma unroll
    for (int q = 0; q < 4; ++q) {
        int o = blockIdx.x * 4096 + q * 1024 + threadIdx.x * 4;
        int c0 = o >> 12, f0 = (o >> 8) & 15, c1 = (o >> 4) & 15, f1 = o & 15;
        int n = c0 * 16 + c1;
        int f = f0 * 16 + f1;
        int k = -1;
        if (n == i0) k = 0; else if (n == i1) k = 1; else if (n == i2) k = 2; else if (n == i3) k = 3;
        float r0, r1, r2, r3;
        if (k >= 0) {
            float4 u = *(const float4*)(fine + ((size_t)(b * 4 + k)) * F_FINE + f);
            r0 = u.x; r1 = u.y; r2 = u.z; r3 = u.w;
        } else {
            float base = coarse[(size_t)b * N_COARSE + n] - LOG_F;
            r0 = r1 = r2 = r3 = base;
        }
        float* p = out + rowb + o;
        __builtin_nontemporal_store(r0, p + 0);
        __builtin_nontemporal_store(r1, p + 1);
        __builtin_nontemporal_store(r2, p + 2);
        __builtin_nontemporal_store(r3, p + 3);
    }
}

extern "C" void kernel_launch(void* const* d_in, const int* in_sizes, int n_in,
                              void* d_out, int out_size, void* d_ws, size_t ws_size,
                              hipStream_t stream) {
    const float* x     = (const float*)d_in[0];
    const float* in_g  = (const float*)d_in[1];
    const float* in_b  = (const float*)d_in[2];
    const float* nop_w = (const float*)d_in[3];
    const float* nop_b = (const float*)d_in[4];
    const float* c_w1  = (const float*)d_in[5];
    const float* c_b1  = (const float*)d_in[6];
    const float* c_w2  = (const float*)d_in[7];
    const float* c_b2  = (const float*)d_in[8];
    const float* c_w3  = (const float*)d_in[9];
    const float* c_b3  = (const float*)d_in[10];
    const float* emb   = (const float*)d_in[11];
    const float* emb_g = (const float*)d_in[12];
    const float* emb_b = (const float*)d_in[13];
    const float* f_w1  = (const float*)d_in[14];
    const float* f_b1  = (const float*)d_in[15];
    const float* f_w2  = (const float*)d_in[16];
    const float* f_b2  = (const float*)d_in[17];
    const float* f_w3  = (const float*)d_in[18];
    const float* f_b3  = (const float*)d_in[19];

    float* ws = (float*)d_ws;
    float* xn      = ws;                         // 2048*512 f32
    float* h1      = xn + 1048576;               // 2048*512 f32
    float* h2      = h1 + 1048576;               // 2048*512 f32
    float* coarse  = h2 + 1048576;               // 2048*256 f32
    float* fine    = coarse + 524288;            // 8192*256 f32
    ushort_t* xn_bf  = (ushort_t*)(fine + 2097152);  // 2048*512 bf16
    ushort_t* e_bf   = xn_bf + 1048576;          // 8192*512
    ushort_t* fh1_bf = e_bf + 4194304;           // 8192*512
    ushort_t* fh2_bf = fh1_bf + 4194304;         // 8192*512
    ushort_t* wt1    = fh2_bf + 4194304;         // 512*1024
    ushort_t* wt2    = wt1 + 524288;             // 512*512
    ushort_t* wt3    = wt2 + 262144;             // 256*512
    int*   idxb   = (int*)(wt3 + 131072);        // 8192
    float* cvals  = (float*)(idxb + 8192);       // 8192

    float* out = (float*)d_out;

    // 1. fused: weight convT + LN + no_op
    prep_kernel<<<896 + BATCH, 256, 0, stream>>>(
        f_w1, f_w2, f_w3, wt1, wt2, wt3,
        x, in_g, in_b, nop_w, nop_b, xn, xn_bf, out);
    // 2-4. coarse MLP (fp32 — top-k fidelity), 64x32 tiles, 2 blocks/CU
    gemm_kernel<true><<<dim3(16, 32), 256, 0, stream>>>(xn, c_w1, c_b1, h1, 512, 512);
    gemm_kernel<true><<<dim3(16, 32), 256, 0, stream>>>(h1, c_w2, c_b2, h2, 512, 512);
    gemm_kernel<false><<<dim3(8, 32), 256, 0, stream>>>(h2, c_w3, c_b3, coarse, 256, 512);
    // 5. fused top-4 + emb gather+LN -> bf16
    topk_embln_kernel<<<BATCH, 256, 0, stream>>>(coarse, emb, emb_g, emb_b, idxb, cvals, e_bf);
    // 6. fh1 = gelu(concat(xn,e) @ f_w1 + f_b1)   MT=64 NT=128, 512 blocks
    mfma_gemm_kernel<64, 128, true, true, true, false><<<dim3(4, 128), 256, 0, stream>>>(
        xn_bf, e_bf, 512, wt1, f_b1, nullptr, fh1_bf, 512, 1024);
    // 7. fh2 = gelu(fh1 @ f_w2 + f_b2)
    mfma_gemm_kernel<64, 128, false, true, true, false><<<dim3(4, 128), 256, 0, stream>>>(
        fh1_bf, nullptr, 0, wt2, f_b2, nullptr, fh2_bf, 512, 512);
    // 8. fine = cvals + log_softmax(fh2 @ f_w3 + f_b3)  — fused epilogue, full 256-col rows
    mfma_gemm_kernel<64, 256, false, false, false, true><<<dim3(1, 128), 256, 0, stream>>>(
        fh2_bf, nullptr, 0, wt3, f_b3, cvals, fine, 256, 512);
    // 9. scatter to permuted output
    scatter_kernel<<<dim3(16, BATCH), 256, 0, stream>>>(coarse, fine, idxb, out);
}

// Round 7
// 760.201 us; speedup vs baseline: 1.2368x; 1.0227x over previous
//
#include <hip/hip_runtime.h>
#include <math.h>

#define BATCH 2048
#define CH 512
#define N_COARSE 256
#define F_FINE 256
#define K_TOP 4
#define OUT_STRIDE 65537  // 1 + N*F

typedef unsigned short ushort_t;
typedef __bf16 bf16x8 __attribute__((ext_vector_type(8)));
typedef float f32x4 __attribute__((ext_vector_type(4)));

__device__ __forceinline__ float gelu_tanh(float x) {
    float x3 = x * x * x;
    float t = tanhf(0.7978845608028654f * (x + 0.044715f * x3));
    return 0.5f * x * (1.0f + t);
}

__device__ __forceinline__ ushort_t f2bf(float f) {
    unsigned u = __float_as_uint(f);
    unsigned r = (u + 0x7FFF + ((u >> 16) & 1)) >> 16;
    return (ushort_t)r;
}
__device__ __forceinline__ float bf2f(ushort_t h) {
    return __uint_as_float(((unsigned)h) << 16);
}

// ---------------- fused prep ----------------
// blocks 0..895: fine weights convT bf16; 896..1535: coarse weights convT hi/lo split;
// 1536..3583: LN(x)+no_op, writing xnsp = [hi(512)|lo(512)] bf16 rows.
__global__ __launch_bounds__(256) void prep_kernel(
    const float* __restrict__ f_w1, const float* __restrict__ f_w2, const float* __restrict__ f_w3,
    ushort_t* __restrict__ wt1, ushort_t* __restrict__ wt2, ushort_t* __restrict__ wt3,
    const float* __restrict__ c_w1, const float* __restrict__ c_w2, const float* __restrict__ c_w3,
    ushort_t* __restrict__ cwt1, ushort_t* __restrict__ cwt2, ushort_t* __restrict__ cwt3,
    const float* __restrict__ x, const float* __restrict__ g, const float* __restrict__ b,
    const float* __restrict__ nop_w, const float* __restrict__ nop_b,
    ushort_t* __restrict__ xnsp, float* __restrict__ out)
{
    __shared__ float s[32][33];
    int blk = blockIdx.x;
    int t = threadIdx.x;
    if (blk < 1536) {
        const float* W; ushort_t* Wt; int Kd, Nd, gx, gy; bool split;
        if (blk < 512)       { W=f_w1; Wt=wt1; Kd=1024; Nd=512; gx=blk&15; gy=blk>>4; split=false; }
        else if (blk < 768)  { int u=blk-512;  W=f_w2; Wt=wt2; Kd=512; Nd=512; gx=u&15; gy=u>>4; split=false; }
        else if (blk < 896)  { int u=blk-768;  W=f_w3; Wt=wt3; Kd=512; Nd=256; gx=u&7;  gy=u>>3; split=false; }
        else if (blk < 1152) { int u=blk-896;  W=c_w1; Wt=cwt1; Kd=512; Nd=512; gx=u&15; gy=u>>4; split=true; }
        else if (blk < 1408) { int u=blk-1152; W=c_w2; Wt=cwt2; Kd=512; Nd=512; gx=u&15; gy=u>>4; split=true; }
        else                 { int u=blk-1408; W=c_w3; Wt=cwt3; Kd=512; Nd=256; gx=u&7;  gy=u>>3; split=true; }
        int tx = t & 31, ty = t >> 5;
        int n0 = gx * 32, k0 = gy * 32;
        #pragma unroll
        for (int i = 0; i < 4; ++i) {
            int r = ty + i * 8;
            s[r][tx] = W[(size_t)(k0 + r) * Nd + n0 + tx];
        }
        __syncthreads();
        if (!split) {
            #pragma unroll
            for (int i = 0; i < 4; ++i) {
                int r = ty + i * 8;
                Wt[(size_t)(n0 + r) * Kd + k0 + tx] = f2bf(s[tx][r]);
            }
        } else {
            #pragma unroll
            for (int i = 0; i < 4; ++i) {
                int r = ty + i * 8;
                float v = s[tx][r];
                ushort_t h = f2bf(v);
                Wt[(size_t)(n0 + r) * 1024 + k0 + tx] = h;
                Wt[(size_t)(n0 + r) * 1024 + 512 + k0 + tx] = f2bf(v - bf2f(h));
            }
        }
    } else {
        float* red = &s[0][0];
        int row = blk - 1536;
        int lane = t & 63, wave = t >> 6;
        const float* xr = x + (size_t)row * CH;
        float v0 = xr[t], v1 = xr[t + 256];
        float sm = v0 + v1, ss = v0 * v0 + v1 * v1;
        #pragma unroll
        for (int off = 32; off; off >>= 1) { sm += __shfl_xor(sm, off); ss += __shfl_xor(ss, off); }
        if (lane == 0) { red[wave] = sm; red[4 + wave] = ss; }
        __syncthreads();
        sm = red[0] + red[1] + red[2] + red[3];
        ss = red[4] + red[5] + red[6] + red[7];
        float mean = sm * (1.0f / CH);
        float var = ss * (1.0f / CH) - mean * mean;
        float rsq = rsqrtf(var + 1e-5f);
        float xn0 = (v0 - mean) * rsq * g[t] + b[t];
        float xn1 = (v1 - mean) * rsq * g[t + 256] + b[t + 256];
        ushort_t* xr2 = xnsp + (size_t)row * 1024;
        ushort_t h0 = f2bf(xn0), h1v = f2bf(xn1);
        xr2[t] = h0; xr2[t + 256] = h1v;
        xr2[512 + t] = f2bf(xn0 - bf2f(h0));
        xr2[512 + t + 256] = f2bf(xn1 - bf2f(h1v));
        float d = xn0 * nop_w[t] + xn1 * nop_w[t + 256];
        #pragma unroll
        for (int off = 32; off; off >>= 1) d += __shfl_xor(d, off);
        __syncthreads();
        if (lane == 0) red[wave] = d;
        __syncthreads();
        if (t == 0) out[(size_t)row * OUT_STRIDE] = red[0] + red[1] + red[2] + red[3] + nop_b[0];
    }
}

// ---------------- bf16 MFMA GEMM, MTxNT tile, BK=32, reg-prefetch + LDS dbuf ----------------
// MODE 0: A1 row-major stride Ktot.
// MODE 1: concat — k<512: A1[row>>2] stride 1024 (hi half of xnsp); k>=512: A2[row] stride 512.
// MODE 2: 3-term split — A phys [hi|lo] stride 1024, W phys [hi|lo] stride 1024, Ktot=1536:
//         k in [0,512): Ahi*Whi; [512,1024): Ahi*Wlo; [1024,1536): Alo*Whi.
// OUTM 0: bf16 out, gelu, stride Nd. OUTM 1: split hi/lo bf16 out stride 1024, gelu.
// OUTM 2: f32 out, no gelu, stride Nd. OUTM 3: f32 out = cvals + log_softmax (Nd==NT==256).
template<int MODE, int MT, int NT, int OUTM>
__global__ __launch_bounds__(256) void mfma_gemm_kernel(
    const ushort_t* __restrict__ A1, const ushort_t* __restrict__ A2,
    const ushort_t* __restrict__ Wt, const float* __restrict__ bias,
    const float* __restrict__ cvals, void* __restrict__ Cout, int Nd, int Ktot)
{
    constexpr int AI = MT / 64, BI = NT / 64;
    constexpr int FI = MT / 32, FJ = NT / 32;
    __shared__ ushort_t As[2][MT * 32];
    __shared__ ushort_t Bs[2][NT * 32];
    __shared__ float mxs[64 * 2];
    __shared__ float ses[64 * 2];
    int t = threadIdx.x;
    int n0 = blockIdx.x * NT, m0 = blockIdx.y * MT;
    int wave = t >> 6, lane = t & 63;
    int wm = (wave & 1) * (MT / 2), wn = (wave >> 1) * (NT / 2);
    int lr = lane & 15, quad = lane >> 4;

    f32x4 acc[FI][FJ] = {};
    float4 aReg[AI], bReg[BI];

    auto loadAB = [&](int k0) {
        int aoff = (MODE == 2) ? ((k0 >= 1024) ? k0 - 512 : (k0 & 511)) : k0;
        int woff = (MODE == 2) ? ((k0 >= 1024) ? k0 - 1024 : k0) : k0;
        #pragma unroll
        for (int i = 0; i < AI; ++i) {
            int c = i * 256 + t, r = c >> 2, q = (c & 3) * 8;
            int gr = m0 + r;
            const ushort_t* ap;
            if (MODE == 1)      ap = (k0 < 512) ? A1 + (size_t)(gr >> 2) * 1024 + k0 + q
                                                : A2 + (size_t)gr * 512 + (k0 - 512) + q;
            else if (MODE == 2) ap = A1 + (size_t)gr * 1024 + aoff + q;
            else                ap = A1 + (size_t)gr * Ktot + k0 + q;
            aReg[i] = *(const float4*)ap;
        }
        #pragma unroll
        for (int i = 0; i < BI; ++i) {
            int c = i * 256 + t, r = c >> 2, q = (c & 3) * 8;
            size_t wstride = (MODE == 2) ? 1024 : (size_t)Ktot;
            bReg[i] = *(const float4*)(Wt + (size_t)(n0 + r) * wstride + woff + q);
        }
    };
    auto storeAB = [&](int p) {
        #pragma unroll
        for (int i = 0; i < AI; ++i) { int c = i * 256 + t; *(float4*)&As[p][c * 8] = aReg[i]; }
        #pragma unroll
        for (int i = 0; i < BI; ++i) { int c = i * 256 + t; *(float4*)&Bs[p][c * 8] = bReg[i]; }
    };

    loadAB(0);
    storeAB(0);
    int steps = Ktot >> 5;
    int p = 0;
    for (int s = 0; s < steps; ++s) {
        __syncthreads();
        if (s + 1 < steps) loadAB((s + 1) * 32);
        bf16x8 af[FI], bfr[FJ];
        #pragma unroll
        for (int i = 0; i < FI; ++i)
            af[i] = *(const bf16x8*)&As[p][(wm + i * 16 + lr) * 32 + quad * 8];
        #pragma unroll
        for (int j = 0; j < FJ; ++j)
            bfr[j] = *(const bf16x8*)&Bs[p][(wn + j * 16 + lr) * 32 + quad * 8];
        #pragma unroll
        for (int i = 0; i < FI; ++i)
            #pragma unroll
            for (int j = 0; j < FJ; ++j)
                acc[i][j] = __builtin_amdgcn_mfma_f32_16x16x32_bf16(af[i], bfr[j], acc[i][j], 0, 0, 0);
        if (s + 1 < steps) storeAB(p ^ 1);
        p ^= 1;
    }

    if (OUTM == 3) {
        float bv[FJ];
        #pragma unroll
        for (int j = 0; j < FJ; ++j) bv[j] = bias[wn + j * 16 + lr];
        int half = wave >> 1;
        float rmx[FI][4];
        #pragma unroll
        for (int i = 0; i < FI; ++i)
            #pragma unroll
            for (int r = 0; r < 4; ++r) {
                float m = -1e30f;
                #pragma unroll
                for (int j = 0; j < FJ; ++j) m = fmaxf(m, acc[i][j][r] + bv[j]);
                #pragma unroll
                for (int mk = 1; mk < 16; mk <<= 1) m = fmaxf(m, __shfl_xor(m, mk));
                if (lr == 0) mxs[(wm + i * 16 + quad * 4 + r) * 2 + half] = m;
            }
        __syncthreads();
        #pragma unroll
        for (int i = 0; i < FI; ++i)
            #pragma unroll
            for (int r = 0; r < 4; ++r) {
                int rl = wm + i * 16 + quad * 4 + r;
                rmx[i][r] = fmaxf(mxs[rl * 2], mxs[rl * 2 + 1]);
            }
        #pragma unroll
        for (int i = 0; i < FI; ++i)
            #pragma unroll
            for (int r = 0; r < 4; ++r) {
                float sv = 0.f;
                #pragma unroll
                for (int j = 0; j < FJ; ++j) sv += expf(acc[i][j][r] + bv[j] - rmx[i][r]);
                #pragma unroll
                for (int mk = 1; mk < 16; mk <<= 1) sv += __shfl_xor(sv, mk);
                if (lr == 0) ses[(wm + i * 16 + quad * 4 + r) * 2 + half] = sv;
            }
        __syncthreads();
        float* outp = (float*)Cout;
        #pragma unroll
        for (int i = 0; i < FI; ++i)
            #pragma unroll
            for (int r = 0; r < 4; ++r) {
                int rl = wm + i * 16 + quad * 4 + r;
                float se = ses[rl * 2] + ses[rl * 2 + 1];
                float addc = cvals[m0 + rl] - rmx[i][r] - logf(se);
                #pragma unroll
                for (int j = 0; j < FJ; ++j)
                    outp[(size_t)(m0 + rl) * Nd + wn + j * 16 + lr] = acc[i][j][r] + bv[j] + addc;
            }
    } else {
        #pragma unroll
        for (int j = 0; j < FJ; ++j) {
            int col = n0 + wn + j * 16 + lr;
            float bvv = bias[col];
            #pragma unroll
            for (int i = 0; i < FI; ++i) {
                #pragma unroll
                for (int r = 0; r < 4; ++r) {
                    int row = m0 + wm + i * 16 + quad * 4 + r;
                    float val = acc[i][j][r] + bvv;
                    if (OUTM == 0) {
                        ((ushort_t*)Cout)[(size_t)row * Nd + col] = f2bf(gelu_tanh(val));
                    } else if (OUTM == 1) {
                        float gv = gelu_tanh(val);
                        ushort_t h = f2bf(gv);
                        ((ushort_t*)Cout)[(size_t)row * 1024 + col] = h;
                        ((ushort_t*)Cout)[(size_t)row * 1024 + 512 + col] = f2bf(gv - bf2f(h));
                    } else {
                        ((float*)Cout)[(size_t)row * Nd + col] = val;
                    }
                }
            }
        }
    }
}

// ---------------- fused: top-4 per row + gather+LN of the 4 emb rows -> bf16 ----------------
__global__ __launch_bounds__(256) void topk_embln_kernel(
    const float* __restrict__ coarse, const float* __restrict__ emb,
    const float* __restrict__ g, const float* __restrict__ b,
    int* __restrict__ idx, float* __restrict__ cvals, ushort_t* __restrict__ e_bf)
{
    int brow = blockIdx.x;
    int t = threadIdx.x;
    int wave = t >> 6, lane = t & 63;
    __shared__ int sidx[4];

    if (wave == 0) {
        const float* cr = coarse + (size_t)brow * N_COARSE;
        float v[4]; int id[4];
        #pragma unroll
        for (int j = 0; j < 4; ++j) { v[j] = cr[lane + 64 * j]; id[j] = lane + 64 * j; }
        #pragma unroll
        for (int r = 0; r < K_TOP; ++r) {
            float bv = v[0]; int bi = id[0];
            #pragma unroll
            for (int j = 1; j < 4; ++j)
                if (v[j] > bv || (v[j] == bv && id[j] < bi)) { bv = v[j]; bi = id[j]; }
            #pragma unroll
            for (int off = 32; off; off >>= 1) {
                float ov = __shfl_xor(bv, off); int oi = __shfl_xor(bi, off);
                if (ov > bv || (ov == bv && oi < bi)) { bv = ov; bi = oi; }
            }
            if ((bi & 63) == lane) v[bi >> 6] = -INFINITY;
            if (lane == 0) {
                sidx[r] = bi;
                idx[brow * K_TOP + r] = bi;
                cvals[brow * K_TOP + r] = bv;
            }
        }
    }
    __syncthreads();

    int n = sidx[wave];
    const float* er = emb + (size_t)n * CH + lane * 8;
    float4 u0 = *(const float4*)er;
    float4 u1 = *(const float4*)(er + 4);
    float s  = u0.x + u0.y + u0.z + u0.w + u1.x + u1.y + u1.z + u1.w;
    float ss = u0.x * u0.x + u0.y * u0.y + u0.z * u0.z + u0.w * u0.w
             + u1.x * u1.x + u1.y * u1.y + u1.z * u1.z + u1.w * u1.w;
    #pragma unroll
    for (int off = 32; off; off >>= 1) { s += __shfl_xor(s, off); ss += __shfl_xor(ss, off); }
    float mean = s * (1.0f / CH);
    float var = ss * (1.0f / CH) - mean * mean;
    float rsq = rsqrtf(var + 1e-5f);
    float4 g0 = *(const float4*)(g + lane * 8), g1 = *(const float4*)(g + lane * 8 + 4);
    float4 b0 = *(const float4*)(b + lane * 8), b1 = *(const float4*)(b + lane * 8 + 4);
    uint4 pk;
    pk.x = (unsigned)f2bf((u0.x - mean) * rsq * g0.x + b0.x) |
           ((unsigned)f2bf((u0.y - mean) * rsq * g0.y + b0.y) << 16);
    pk.y = (unsigned)f2bf((u0.z - mean) * rsq * g0.z + b0.z) |
           ((unsigned)f2bf((u0.w - mean) * rsq * g0.w + b0.w) << 16);
    pk.z = (unsigned)f2bf((u1.x - mean) * rsq * g1.x + b1.x) |
           ((unsigned)f2bf((u1.y - mean) * rsq * g1.y + b1.y) << 16);
    pk.w = (unsigned)f2bf((u1.z - mean) * rsq * g1.z + b1.z) |
           ((unsigned)f2bf((u1.w - mean) * rsq * g1.w + b1.w) << 16);
    *(uint4*)(e_bf + (size_t)(brow * K_TOP + wave) * CH + lane * 8) = pk;
}

// ---------------- final scatter into permuted dense output ----------------
__global__ __launch_bounds__(256) void scatter_kernel(
    const float* __restrict__ coarse, const float* __restrict__ fine,
    const int* __restrict__ idx, float* __restrict__ out)
{
    const float LOG_F = 5.545177444479562f;
    int b = blockIdx.y;
    __shared__ int sidx[4];
    if (threadIdx.x < 4) sidx[threadIdx.x] = idx[b * 4 + threadIdx.x];
    __syncthreads();
    int i0 = sidx[0], i1 = sidx[1], i2 = sidx[2], i3 = sidx[3];
    size_t rowb = (size_t)b * OUT_STRIDE + 1;
    #pragma unroll
    for (int q = 0; q < 4; ++q) {
        int o = blockIdx.x * 4096 + q * 1024 + threadIdx.x * 4;
        int c0 = o >> 12, f0 = (o >> 8) & 15, c1 = (o >> 4) & 15, f1 = o & 15;
        int n = c0 * 16 + c1;
        int f = f0 * 16 + f1;
        int k = -1;
        if (n == i0) k = 0; else if (n == i1) k = 1; else if (n == i2) k = 2; else if (n == i3) k = 3;
        float r0, r1, r2, r3;
        if (k >= 0) {
            float4 u = *(const float4*)(fine + ((size_t)(b * 4 + k)) * F_FINE + f);
            r0 = u.x; r1 = u.y; r2 = u.z; r3 = u.w;
        } else {
            float base = coarse[(size_t)b * N_COARSE + n] - LOG_F;
            r0 = r1 = r2 = r3 = base;
        }
        float* p = out + rowb + o;
        __builtin_nontemporal_store(r0, p + 0);
        __builtin_nontemporal_store(r1, p + 1);
        __builtin_nontemporal_store(r2, p + 2);
        __builtin_nontemporal_store(r3, p + 3);
    }
}

extern "C" void kernel_launch(void* const* d_in, const int* in_sizes, int n_in,
                              void* d_out, int out_size, void* d_ws, size_t ws_size,
                              hipStream_t stream) {
    const float* x     = (const float*)d_in[0];
    const float* in_g  = (const float*)d_in[1];
    const float* in_b  = (const float*)d_in[2];
    const float* nop_w = (const float*)d_in[3];
    const float* nop_b = (const float*)d_in[4];
    const float* c_w1  = (const float*)d_in[5];
    const float* c_b1  = (const float*)d_in[6];
    const float* c_w2  = (const float*)d_in[7];
    const float* c_b2  = (const float*)d_in[8];
    const float* c_w3  = (const float*)d_in[9];
    const float* c_b3  = (const float*)d_in[10];
    const float* emb   = (const float*)d_in[11];
    const float* emb_g = (const float*)d_in[12];
    const float* emb_b = (const float*)d_in[13];
    const float* f_w1  = (const float*)d_in[14];
    const float* f_b1  = (const float*)d_in[15];
    const float* f_w2  = (const float*)d_in[16];
    const float* f_b2  = (const float*)d_in[17];
    const float* f_w3  = (const float*)d_in[18];
    const float* f_b3  = (const float*)d_in[19];

    float* ws = (float*)d_ws;
    float* coarse  = ws;                          // 2048*256 f32
    float* fine    = coarse + 524288;             // 8192*256 f32
    ushort_t* xnsp   = (ushort_t*)(fine + 2097152);  // 2048*1024 bf16 [hi|lo]
    ushort_t* h1sp   = xnsp + 2097152;            // 2048*1024
    ushort_t* h2sp   = h1sp + 2097152;            // 2048*1024
    ushort_t* e_bf   = h2sp + 2097152;            // 8192*512
    ushort_t* fh1_bf = e_bf + 4194304;            // 8192*512
    ushort_t* fh2_bf = fh1_bf + 4194304;          // 8192*512
    ushort_t* wt1    = fh2_bf + 4194304;          // 512*1024
    ushort_t* wt2    = wt1 + 524288;              // 512*512
    ushort_t* wt3    = wt2 + 262144;              // 256*512
    ushort_t* cwt1   = wt3 + 131072;              // 512*1024
    ushort_t* cwt2   = cwt1 + 524288;             // 512*1024
    ushort_t* cwt3   = cwt2 + 524288;             // 256*1024
    int*   idxb   = (int*)(cwt3 + 262144);        // 8192
    float* cvals  = (float*)(idxb + 8192);        // 8192

    float* out = (float*)d_out;

    // 1. fused prep: fine convT + coarse convT hi/lo + LN+no_op
    prep_kernel<<<3584, 256, 0, stream>>>(
        f_w1, f_w2, f_w3, wt1, wt2, wt3,
        c_w1, c_w2, c_w3, cwt1, cwt2, cwt3,
        x, in_g, in_b, nop_w, nop_b, xnsp, out);
    // 2-4. coarse MLP via 3-term split-bf16 MFMA (K=1536), hi/lo hidden activations
    mfma_gemm_kernel<2, 64, 64, 1><<<dim3(8, 32), 256, 0, stream>>>(
        xnsp, nullptr, cwt1, c_b1, nullptr, h1sp, 512, 1536);
    mfma_gemm_kernel<2, 64, 64, 1><<<dim3(8, 32), 256, 0, stream>>>(
        h1sp, nullptr, cwt2, c_b2, nullptr, h2sp, 512, 1536);
    mfma_gemm_kernel<2, 64, 64, 2><<<dim3(4, 32), 256, 0, stream>>>(
        h2sp, nullptr, cwt3, c_b3, nullptr, coarse, 256, 1536);
    // 5. fused top-4 + emb gather+LN -> bf16
    topk_embln_kernel<<<BATCH, 256, 0, stream>>>(coarse, emb, emb_g, emb_b, idxb, cvals, e_bf);
    // 6. fh1 = gelu(concat(xn_hi, e) @ f_w1 + f_b1)
    mfma_gemm_kernel<1, 64, 128, 0><<<dim3(4, 128), 256, 0, stream>>>(
        xnsp, e_bf, wt1, f_b1, nullptr, fh1_bf, 512, 1024);
    // 7. fh2 = gelu(fh1 @ f_w2 + f_b2)
    mfma_gemm_kernel<0, 64, 128, 0><<<dim3(4, 128), 256, 0, stream>>>(
        fh1_bf, nullptr, wt2, f_b2, nullptr, fh2_bf, 512, 512);
    // 8. fine = cvals + log_softmax(fh2 @ f_w3 + f_b3)
    mfma_gemm_kernel<0, 64, 256, 3><<<dim3(1, 128), 256, 0, stream>>>(
        fh2_bf, nullptr, wt3, f_b3, cvals, fine, 256, 512);
    // 9. scatter to permuted output
    scatter_kernel<<<dim3(16, BATCH), 256, 0, stream>>>(coarse, fine, idxb, out);
}